// Round 9
// baseline (172.339 us; speedup 1.0000x reference)
//
#include <hip/hip_runtime.h>
#include <hip/hip_bf16.h>
#include <math.h>

#define INV_SQRT2F 0.70710678118654752440f
#define AS1 __attribute__((address_space(1)))
#define AS3 __attribute__((address_space(3)))

typedef __attribute__((ext_vector_type(8))) short short8;
typedef __attribute__((ext_vector_type(4))) float floatx4;

// ---------------- compile-time algebra tables ----------------
struct Tables {
  int   kof[8][8];
  float cs[8][8];
  int   widx[8][8];
};
constexpr int t_bm(int i){ constexpr int t[8] = {0,1,2,4,3,5,6,7}; return t[i]; }
constexpr int t_idx(int b){ constexpr int t[8] = {0,1,2,4,3,5,6,7}; return t[b]; }
constexpr int t_gr(int i){ constexpr int t[8] = {0,1,1,1,2,2,2,3}; return t[i]; }
constexpr int t_pc(int x){ int c=0; while(x){ c += x&1; x >>= 1; } return c; }
constexpr float t_sign(int a, int b){
  float s = 1.f; int aa = a >> 1;
  while(aa){ if(t_pc(aa & b) & 1) s = -s; aa >>= 1; }
  return s;
}
constexpr int   c_kof(int j,int i){ return t_idx(t_bm(i)^t_bm(j)); }
constexpr float c_cs(int j,int i){ return t_sign(t_bm(i), t_bm(c_kof(j,i))); }
constexpr int   c_widx(int j,int i){ return t_gr(i)*16 + t_gr(j)*4 + t_gr(c_kof(j,i)); }
constexpr Tables mkTables(){
  Tables T{};
  for(int j=0;j<8;j++) for(int i=0;i<8;i++){
    T.kof[j][i]  = c_kof(j,i);
    T.cs[j][i]   = c_cs(j,i);
    T.widx[j][i] = c_widx(j,i);
  }
  return T;
}
__device__ const Tables d_TB = mkTables();

__device__ __forceinline__ float rcpf(float v){ return __builtin_amdgcn_rcpf(v); }
__device__ __forceinline__ float sigf(float z){ return rcpf(1.f + __expf(-z)); }
__device__ __forceinline__ int gradeOfIdx(int i){ return (i==0)?0:((i<4)?1:((i<7)?2:3)); }
__device__ __forceinline__ short f2bf(float v){
  __hip_bfloat16 h = __float2bfloat16(v);
  short s; __builtin_memcpy(&s, &h, 2); return s;
}
__device__ __forceinline__ float bf2f(short s){
  unsigned int w = ((unsigned int)(unsigned short)s) << 16;
  float f; __builtin_memcpy(&f, &w, 4); return f;
}
__device__ __forceinline__ void norm8v(float* v, float4 na){
  float s0 = sigf(na.x)*(fabsf(v[0])-1.f)+1.f+1e-6f;
  float s1 = sigf(na.y)*(sqrtf(v[1]*v[1]+v[2]*v[2]+v[3]*v[3])-1.f)+1.f+1e-6f;
  float s2 = sigf(na.z)*(sqrtf(v[4]*v[4]+v[5]*v[5]+v[6]*v[6])-1.f)+1.f+1e-6f;
  float s3 = sigf(na.w)*(fabsf(v[7])-1.f)+1.f+1e-6f;
  float r0 = rcpf(s0), r1 = rcpf(s1), r2 = rcpf(s2), r3 = rcpf(s3);
  v[0]*=r0; v[1]*=r1; v[2]*=r1; v[3]*=r1; v[4]*=r2; v[5]*=r2; v[6]*=r2; v[7]*=r3;
}

// ---------------- pack_x: x fp32 [b][m][8] -> 8 bf16 planes [i][b*512+m] ----------------
__global__ __launch_bounds__(256) void pack_x(const float* __restrict__ x,
                                              __hip_bfloat16* __restrict__ xP){
  size_t e = (size_t)blockIdx.x*256 + threadIdx.x;
  float4 u0 = *(const float4*)(x + e*8);
  float4 u1 = *(const float4*)(x + e*8 + 4);
  float u[8] = {u0.x,u0.y,u0.z,u0.w,u1.x,u1.y,u1.z,u1.w};
  #pragma unroll
  for(int i=0;i<8;i++) xP[(size_t)i*2097152 + e] = __float2bfloat16(u[i]);
}

// ---------------- pack_misc: fused small weight packs ----------------
__global__ __launch_bounds__(256) void pack_misc(const float* __restrict__ w,
                                                 const float* __restrict__ gpw,
                                                 const float* __restrict__ wl,
                                                 const float* __restrict__ w2r,
                                                 const float* __restrict__ w2l,
                                                 const float* __restrict__ w3r,
                                                 const float* __restrict__ gw3,
                                                 const float* __restrict__ w3l,
                                                 __hip_bfloat16* __restrict__ wP,
                                                 __hip_bfloat16* __restrict__ Bpack,
                                                 __hip_bfloat16* __restrict__ wlP,
                                                 __hip_bfloat16* __restrict__ w2rP,
                                                 __hip_bfloat16* __restrict__ w2lP,
                                                 __hip_bfloat16* __restrict__ w3rP,
                                                 __hip_bfloat16* __restrict__ Bp3){
  const int bx = blockIdx.x;
  if(bx < 1024){
    size_t e = (size_t)bx*256 + threadIdx.x;
    float4 u = *(const float4*)(w + e*4);
    float v[4] = {u.x,u.y,u.z,u.w};
    #pragma unroll
    for(int g=0; g<4; g++) wP[(size_t)g*262144 + e] = __float2bfloat16(v[g]);
  } else if(bx < 1536){
    int t = (bx-1024)*256 + threadIdx.x;          // j*16384 + n*32 + m
    int j = t >> 14; int n = (t >> 5) & 511; int m = t & 31;
    const float* src = gpw + ((size_t)m*512 + n)*64;
    short8 o;
    #pragma unroll
    for(int jj=0; jj<8; jj++){
      if(jj == j){
        #pragma unroll
        for(int i=0;i<8;i++) o[i] = f2bf(c_cs(jj,i) * src[c_widx(jj,i)]);
      }
    }
    int q = n & 3;
    *(short8*)(Bpack + (size_t)(n>>2)*8192 + j*1024 + q*256 + m*8) = o;
  } else if(bx < 2048){
    int t2 = (bx-1536)*256 + threadIdx.x;         // j*16384 + m*512 + n
    int j = t2 >> 14; int m = (t2 >> 9) & 31; int n = t2 & 511;
    int g = gradeOfIdx(j);
    wlP[t2] = __float2bfloat16(wl[((size_t)m*512 + n)*4 + g]);
  } else if(bx < 2144){
    int t = (bx-2048)*256 + threadIdx.x;
    int which = t >> 13; int r = t & 8191;
    int j = r >> 10; int n = (r >> 5) & 31; int m = r & 31;
    int g = gradeOfIdx(j);
    const float* src = (which==0) ? w2r : (which==1) ? w2l : w3r;
    __hip_bfloat16* dst = (which==0) ? w2rP : (which==1) ? w2lP : w3rP;
    dst[r] = __float2bfloat16(src[((size_t)n*32 + m)*4 + g]);
  } else {
    int t2 = (bx-2144)*256 + threadIdx.x;         // j*4608 + mo*288 + k
    if(t2 >= 36864) return;
    int j = t2 / 4608; int rem = t2 - j*4608;
    int mo = rem / 288; int k = rem - mo*288;
    float v = 0.f;
    if(mo < 9){
      if(k < 256){
        int n = k >> 3, i = k & 7;
        v = d_TB.cs[j][i] * gw3[((size_t)mo*32 + n)*64 + d_TB.widx[j][i]];
      } else {
        int n = k - 256;
        v = w3l[((size_t)mo*32 + n)*4 + gradeOfIdx(j)];
      }
    }
    Bp3[t2] = __float2bfloat16(v);
  }
}

// ---------------- K1 MFMA: linrP[i][b][n] = sum_m xP[i][b][m] * wP[g(i)][n][m] ----------------
// BM=128, BN=128, BK=64; grid (32,4,8)
__global__ __launch_bounds__(256) void k1_mfma(const __hip_bfloat16* __restrict__ xP,
                                               const __hip_bfloat16* __restrict__ wP,
                                               __hip_bfloat16* __restrict__ linrP){
  __shared__ __align__(16) char lds[32768];
  char* As = lds;
  char* Bs = lds + 16384;
  const int tid = threadIdx.x;
  const int l   = tid & 63;
  const int w   = tid >> 6;
  const int i   = blockIdx.z;
  const int g   = gradeOfIdx(i);
  const size_t b0 = (size_t)blockIdx.x * 128;
  const size_t n0 = (size_t)blockIdx.y * 128;
  const __hip_bfloat16* Ag = xP + (size_t)i*2097152;
  const __hip_bfloat16* Bg = wP + (size_t)g*262144;

  const int wave_m = (w & 1) * 64;
  const int wave_n = (w >> 1) * 64;
  const int srow = l >> 3;
  const int scol = ((l & 7) ^ srow) * 8;

  floatx4 acc[4][4] = {};

  for(int kt = 0; kt < 512; kt += 64){
    #pragma unroll
    for(int it=0; it<4; it++){
      int c   = it*4 + w;
      int row = c*8 + srow;
      const __hip_bfloat16* sa = Ag + (b0 + row)*512 + kt + scol;
      const __hip_bfloat16* sb = Bg + (n0 + row)*512 + kt + scol;
      __builtin_amdgcn_global_load_lds((const AS1 void*)sa, (AS3 void*)(As + c*1024 + l*16), 16, 0, 0);
      __builtin_amdgcn_global_load_lds((const AS1 void*)sb, (AS3 void*)(Bs + c*1024 + l*16), 16, 0, 0);
    }
    __syncthreads();
    #pragma unroll
    for(int ks=0; ks<2; ks++){
      short8 af[4], bf[4];
      #pragma unroll
      for(int f=0; f<4; f++){
        int rA = wave_m + f*16 + (l & 15);
        int ca = (ks*64 + (l>>4)*16) ^ ((rA & 7) << 4);
        af[f] = *(const short8*)(As + rA*128 + ca);
        int rB = wave_n + f*16 + (l & 15);
        int cb = (ks*64 + (l>>4)*16) ^ ((rB & 7) << 4);
        bf[f] = *(const short8*)(Bs + rB*128 + cb);
      }
      #pragma unroll
      for(int mf=0; mf<4; mf++){
        #pragma unroll
        for(int nf=0; nf<4; nf++){
          acc[mf][nf] = __builtin_amdgcn_mfma_f32_16x16x32_bf16(af[mf], bf[nf], acc[mf][nf], 0, 0, 0);
        }
      }
    }
    __syncthreads();
  }
  __hip_bfloat16* outp = linrP + (size_t)i*2097152;
  #pragma unroll
  for(int mf=0; mf<4; mf++){
    #pragma unroll
    for(int nf=0; nf<4; nf++){
      #pragma unroll
      for(int r=0; r<4; r++){
        size_t m = wave_m + mf*16 + ((l>>4)<<2) + r;
        size_t n = wave_n + nf*16 + (l & 15);
        outp[(b0+m)*512 + n0+n] = __float2bfloat16(acc[mf][nf][r]);
      }
    }
  }
}

// ---------------- k_left: leftB[j][b][m] = sum_n xP[j][b][n]*wlP[j][m][n]  (MFMA) ----------------
__global__ __launch_bounds__(256) void k_left(const __hip_bfloat16* __restrict__ xP,
                                              const __hip_bfloat16* __restrict__ wlP,
                                              float* __restrict__ leftB){
  const int tid = threadIdx.x;
  const int l = tid & 63, w = tid >> 6;
  const int j = blockIdx.y;
  const int row = blockIdx.x*64 + w*16 + (l & 15);
  floatx4 acc[2] = {};
  const __hip_bfloat16* Ap = xP + (size_t)j*2097152;
  const __hip_bfloat16* Wp = wlP + (size_t)j*16384;
  for(int nc=0; nc<16; nc++){
    int nb = nc*32 + (l>>4)*8;
    short8 a  = *(const short8*)(Ap + (size_t)row*512 + nb);
    short8 b0 = *(const short8*)(Wp + (l&15)*512 + nb);
    short8 b1 = *(const short8*)(Wp + ((l&15)+16)*512 + nb);
    acc[0] = __builtin_amdgcn_mfma_f32_16x16x32_bf16(a, b0, acc[0], 0, 0, 0);
    acc[1] = __builtin_amdgcn_mfma_f32_16x16x32_bf16(a, b1, acc[1], 0, 0, 0);
  }
  #pragma unroll
  for(int mf=0; mf<2; mf++){
    #pragma unroll
    for(int r=0; r<4; r++){
      int b = blockIdx.x*64 + w*16 + (l>>4)*4 + r;
      leftB[(size_t)j*131072 + b*32 + mf*16 + (l&15)] = acc[mf][r];
    }
  }
}

// ---------------- knorm: normalize linrP planes -> xrI interleaved bf16 [e][k] ----------------
__global__ __launch_bounds__(256) void knorm(const __hip_bfloat16* __restrict__ linrP,
                                             const float* __restrict__ norm_a,
                                             __hip_bfloat16* __restrict__ xrI){
  const size_t base = ((size_t)blockIdx.x*256 + threadIdx.x) * 8;
  const short* lp = (const short*)linrP;
  short8 v[8];
  #pragma unroll
  for(int i=0;i<8;i++) v[i] = *(const short8*)(lp + (size_t)i*2097152 + base);
  short8 o[8];
  #pragma unroll
  for(int s=0;s<8;s++){
    float u[8];
    #pragma unroll
    for(int i=0;i<8;i++) u[i] = bf2f(v[i][s]);
    int n = (int)((base + s) & 511);
    float4 na = *(const float4*)(norm_a + n*4);
    norm8v(u, na);
    #pragma unroll
    for(int i=0;i<8;i++) o[s][i] = f2bf(u[i]);
  }
  short* op = (short*)xrI;
  #pragma unroll
  for(int s=0;s<8;s++) *(short8*)(op + (base+s)*8) = o[s];
}

// ---------------- k2_mfma: fcgp1 product; NS=8, 2-deep x/xrI prefetch ----------------
// Bpack layout: [n>>2][j][q][m][i] — 16KB contiguous per 4-n group.
__global__ __launch_bounds__(256) void k2_mfma(const float* __restrict__ x,
                                               const __hip_bfloat16* __restrict__ xrI,
                                               const __hip_bfloat16* __restrict__ Bpack,
                                               float* __restrict__ h1part){
  const int tid = threadIdx.x;
  const int l = tid & 63, w = tid >> 6;
  const int row = blockIdx.x*64 + w*16 + (l & 15);
  const int nsb = blockIdx.y * 64;
  const int boff = (l>>4)*256 + (l&15)*8;
  floatx4 acc[8][2] = {};

  const size_t e0 = (size_t)row*512 + nsb + (l>>4);
  float4 xa  = *(const float4*)(x + e0*8);
  float4 xb  = *(const float4*)(x + e0*8 + 4);
  short8 xri = *(const short8*)((const short*)xrI + e0*8);

  for(int nc = 0; nc < 16; nc++){
    float4 nxa = xa, nxb = xb; short8 nxri = xri;
    if(nc < 15){
      const size_t e = e0 + (size_t)(nc+1)*4;
      nxa  = *(const float4*)(x + e*8);
      nxb  = *(const float4*)(x + e*8 + 4);
      nxri = *(const short8*)((const short*)xrI + e*8);
    }
    const __hip_bfloat16* bp_nc = Bpack + (size_t)(blockIdx.y*16 + nc)*8192 + boff;
    float xv[8] = {xa.x,xa.y,xa.z,xa.w,xb.x,xb.y,xb.z,xb.w};
    float xr[8];
    #pragma unroll
    for(int i=0;i<8;i++) xr[i] = bf2f(xri[i]);
    // build all 8 A-fragments first (independent ops for the scheduler)
    short8 af[8];
    #pragma unroll
    for(int j=0;j<8;j++){
      #pragma unroll
      for(int i=0;i<8;i++) af[j][i] = f2bf(xv[i] * xr[c_kof(j,i)]);
    }
    #pragma unroll
    for(int j=0;j<8;j++){
      short8 b0 = *(const short8*)(bp_nc + j*1024);
      short8 b1 = *(const short8*)(bp_nc + j*1024 + 128);
      acc[j][0] = __builtin_amdgcn_mfma_f32_16x16x32_bf16(af[j], b0, acc[j][0], 0, 0, 0);
      acc[j][1] = __builtin_amdgcn_mfma_f32_16x16x32_bf16(af[j], b1, acc[j][1], 0, 0, 0);
    }
    xa = nxa; xb = nxb; xri = nxri;
  }
  const int sp = blockIdx.y;
  #pragma unroll
  for(int j=0;j<8;j++){
    #pragma unroll
    for(int mf=0; mf<2; mf++){
      #pragma unroll
      for(int r=0; r<4; r++){
        int b = blockIdx.x*64 + w*16 + (l>>4)*4 + r;
        h1part[((size_t)(sp*8+j))*131072 + b*32 + mf*16 + (l&15)] = acc[j][mf][r];
      }
    }
  }
}

// ---------------- K2b: reduce + left + bias + silu -> h1s f32 + h1P bf16 planes ----------------
__global__ __launch_bounds__(256) void k2b_silu(const float* __restrict__ h1part,
                                                const float* __restrict__ leftB,
                                                const float* __restrict__ bl,
                                                const float* __restrict__ sa,
                                                const float* __restrict__ sb,
                                                float* __restrict__ h1s,
                                                __hip_bfloat16* __restrict__ h1P){
  int idx = blockIdx.x*256 + threadIdx.x;  // b*32+m
  int m = idx & 31;
  float v[8];
  #pragma unroll
  for(int j=0;j<8;j++){
    float s = leftB[(size_t)j*131072 + idx];
    #pragma unroll
    for(int sp=0; sp<8; sp++) s += h1part[((size_t)(sp*8+j))*131072 + idx];
    v[j] = s;
  }
  v[0] += bl[m];
  #pragma unroll
  for(int i=0;i<8;i++) v[i] *= INV_SQRT2F;
  float q1 = v[1]*v[1]+v[2]*v[2]+v[3]*v[3];
  float q2 = v[4]*v[4]+v[5]*v[5]+v[6]*v[6];
  float q3 = v[7]*v[7];
  float4 sa4 = *(const float4*)&sa[m*4];
  float4 sb4 = *(const float4*)&sb[m*4];
  float g0 = sigf(sa4.x*v[0] + sb4.x);
  float g1 = sigf(sa4.y*q1   + sb4.y);
  float g2 = sigf(sa4.z*q2   + sb4.z);
  float g3 = sigf(sa4.w*q3   + sb4.w);
  float o[8] = {g0*v[0], g1*v[1], g1*v[2], g1*v[3], g2*v[4], g2*v[5], g2*v[6], g3*v[7]};
  *(float4*)&h1s[(size_t)idx*8]     = make_float4(o[0],o[1],o[2],o[3]);
  *(float4*)&h1s[(size_t)idx*8 + 4] = make_float4(o[4],o[5],o[6],o[7]);
  #pragma unroll
  for(int j=0;j<8;j++) h1P[(size_t)j*131072 + idx] = __float2bfloat16(o[j]);
}

// ---------------- k3a: linr2/left2 [j][b][n] = sum_m h1P[j][b][m] * w2{r,l}P[j][n][m] ----------------
__global__ __launch_bounds__(256) void k3a(const __hip_bfloat16* __restrict__ h1P,
                                           const __hip_bfloat16* __restrict__ w2rP,
                                           const __hip_bfloat16* __restrict__ w2lP,
                                           float* __restrict__ linr2,
                                           float* __restrict__ left2){
  const int tid = threadIdx.x;
  const int l = tid & 63, w = tid >> 6;
  const int j = blockIdx.y;
  const int row = blockIdx.x*64 + w*16 + (l & 15);
  const int ko = (l>>4)*8;
  short8 a   = *(const short8*)(h1P + (size_t)j*131072 + (size_t)row*32 + ko);
  short8 br0 = *(const short8*)(w2rP + j*1024 + (l&15)*32 + ko);
  short8 br1 = *(const short8*)(w2rP + j*1024 + ((l&15)+16)*32 + ko);
  short8 bl0 = *(const short8*)(w2lP + j*1024 + (l&15)*32 + ko);
  short8 bl1 = *(const short8*)(w2lP + j*1024 + ((l&15)+16)*32 + ko);
  floatx4 aR0 = {}, aR1 = {}, aL0 = {}, aL1 = {};
  aR0 = __builtin_amdgcn_mfma_f32_16x16x32_bf16(a, br0, aR0, 0, 0, 0);
  aR1 = __builtin_amdgcn_mfma_f32_16x16x32_bf16(a, br1, aR1, 0, 0, 0);
  aL0 = __builtin_amdgcn_mfma_f32_16x16x32_bf16(a, bl0, aL0, 0, 0, 0);
  aL1 = __builtin_amdgcn_mfma_f32_16x16x32_bf16(a, bl1, aL1, 0, 0, 0);
  #pragma unroll
  for(int r=0; r<4; r++){
    int b = blockIdx.x*64 + w*16 + (l>>4)*4 + r;
    linr2[(size_t)j*131072 + b*32 + (l&15)]      = aR0[r];
    linr2[(size_t)j*131072 + b*32 + 16 + (l&15)] = aR1[r];
    left2[(size_t)j*131072 + b*32 + (l&15)]      = aL0[r];
    left2[(size_t)j*131072 + b*32 + 16 + (l&15)] = aL1[r];
  }
}

// ---------------- k3b: norm(linr2) -> x2; sgp + left2 + bias + silu -> h2f, h2P ----------------
__global__ __launch_bounds__(256) void k3b(const float* __restrict__ linr2,
                                           const float* __restrict__ left2,
                                           const float* __restrict__ h1s,
                                           const float* __restrict__ na2,
                                           const float* __restrict__ gw2,
                                           const float* __restrict__ b2l,
                                           const float* __restrict__ sa,
                                           const float* __restrict__ sb,
                                           float* __restrict__ h2f,
                                           __hip_bfloat16* __restrict__ h2P){
  int idx = blockIdx.x*256 + threadIdx.x;  // b*32+n
  int n = idx & 31;
  float x2[8];
  #pragma unroll
  for(int j=0;j<8;j++) x2[j] = linr2[(size_t)j*131072 + idx];
  norm8v(x2, *(const float4*)&na2[n*4]);
  float4 h0 = *(const float4*)&h1s[(size_t)idx*8];
  float4 h1 = *(const float4*)&h1s[(size_t)idx*8 + 4];
  float h[8] = {h0.x,h0.y,h0.z,h0.w,h1.x,h1.y,h1.z,h1.w};
  const float* g2 = gw2 + (size_t)n*64;
  float v[8];
  #pragma unroll
  for(int j=0;j<8;j++){
    float pr = 0.f;
    #pragma unroll
    for(int i=0;i<8;i++)
      pr = fmaf(c_cs(j,i) * h[i] * x2[c_kof(j,i)], g2[c_widx(j,i)], pr);
    v[j] = (pr + left2[(size_t)j*131072 + idx] + ((j==0) ? b2l[n] : 0.f)) * INV_SQRT2F;
  }
  float q1 = v[1]*v[1]+v[2]*v[2]+v[3]*v[3];
  float q2 = v[4]*v[4]+v[5]*v[5]+v[6]*v[6];
  float q3 = v[7]*v[7];
  float4 sa4 = *(const float4*)&sa[n*4];
  float4 sb4 = *(const float4*)&sb[n*4];
  float g0 = sigf(sa4.x*v[0] + sb4.x);
  float g1 = sigf(sa4.y*q1   + sb4.y);
  float gg2 = sigf(sa4.z*q2  + sb4.z);
  float g3 = sigf(sa4.w*q3   + sb4.w);
  float o[8] = {g0*v[0], g1*v[1], g1*v[2], g1*v[3], gg2*v[4], gg2*v[5], gg2*v[6], g3*v[7]};
  *(float4*)&h2f[(size_t)idx*8]     = make_float4(o[0],o[1],o[2],o[3]);
  *(float4*)&h2f[(size_t)idx*8 + 4] = make_float4(o[4],o[5],o[6],o[7]);
  #pragma unroll
  for(int j=0;j<8;j++) h2P[(size_t)j*131072 + idx] = __float2bfloat16(o[j]);
}

// ---------------- k3c: linr3[j][b][n] = sum_m h2P[j][b][m] * w3rP[j][n][m] ----------------
__global__ __launch_bounds__(256) void k3c(const __hip_bfloat16* __restrict__ h2P,
                                           const __hip_bfloat16* __restrict__ w3rP,
                                           float* __restrict__ linr3){
  const int tid = threadIdx.x;
  const int l = tid & 63, w = tid >> 6;
  const int j = blockIdx.y;
  const int row = blockIdx.x*64 + w*16 + (l & 15);
  const int ko = (l>>4)*8;
  short8 a   = *(const short8*)(h2P + (size_t)j*131072 + (size_t)row*32 + ko);
  short8 b0  = *(const short8*)(w3rP + j*1024 + (l&15)*32 + ko);
  short8 b1  = *(const short8*)(w3rP + j*1024 + ((l&15)+16)*32 + ko);
  floatx4 a0 = {}, a1 = {};
  a0 = __builtin_amdgcn_mfma_f32_16x16x32_bf16(a, b0, a0, 0, 0, 0);
  a1 = __builtin_amdgcn_mfma_f32_16x16x32_bf16(a, b1, a1, 0, 0, 0);
  #pragma unroll
  for(int r=0; r<4; r++){
    int b = blockIdx.x*64 + w*16 + (l>>4)*4 + r;
    linr3[(size_t)j*131072 + b*32 + (l&15)]      = a0[r];
    linr3[(size_t)j*131072 + b*32 + 16 + (l&15)] = a1[r];
  }
}

// ---------------- k3d: norm(linr3) -> x3; pairP[j][b][n*8+i] = bf16(h2[i]*x3[kof(j,i)]) ----------------
__global__ __launch_bounds__(256) void k3d(const float* __restrict__ linr3,
                                           const float* __restrict__ h2f,
                                           const float* __restrict__ na3,
                                           __hip_bfloat16* __restrict__ pairP){
  int idx = blockIdx.x*256 + threadIdx.x;  // b*32+n
  int n = idx & 31;
  float x3[8];
  #pragma unroll
  for(int j=0;j<8;j++) x3[j] = linr3[(size_t)j*131072 + idx];
  norm8v(x3, *(const float4*)&na3[n*4]);
  float4 h0 = *(const float4*)&h2f[(size_t)idx*8];
  float4 h1 = *(const float4*)&h2f[(size_t)idx*8 + 4];
  float h[8] = {h0.x,h0.y,h0.z,h0.w,h1.x,h1.y,h1.z,h1.w};
  #pragma unroll
  for(int j=0;j<8;j++){
    short8 o;
    #pragma unroll
    for(int i=0;i<8;i++) o[i] = f2bf(h[i] * x3[c_kof(j,i)]);
    *(short8*)(pairP + (size_t)j*1048576 + (size_t)idx*8) = o;
  }
}

// ---------------- k3e: out[b][mo][j] = (sum_k pair/h2 x Bp3 + bias) * c ----------------
__global__ __launch_bounds__(256) void k3e(const __hip_bfloat16* __restrict__ pairP,
                                           const __hip_bfloat16* __restrict__ h2P,
                                           const __hip_bfloat16* __restrict__ Bp3,
                                           const float* __restrict__ b3l,
                                           float* __restrict__ out){
  const int tid = threadIdx.x;
  const int l = tid & 63, w = tid >> 6;
  const int j = blockIdx.y;
  const int row = blockIdx.x*64 + w*16 + (l & 15);
  const int mo = l & 15;
  const int ko = (l>>4)*8;
  floatx4 acc = {};
  const __hip_bfloat16* Ap = pairP + (size_t)j*1048576 + (size_t)row*256;
  const __hip_bfloat16* Bp = Bp3 + (size_t)j*4608 + mo*288;
  #pragma unroll
  for(int kc=0; kc<8; kc++){
    short8 a = *(const short8*)(Ap + kc*32 + ko);
    short8 b = *(const short8*)(Bp + kc*32 + ko);
    acc = __builtin_amdgcn_mfma_f32_16x16x32_bf16(a, b, acc, 0, 0, 0);
  }
  {
    short8 a = *(const short8*)(h2P + (size_t)j*131072 + (size_t)row*32 + ko);
    short8 b = *(const short8*)(Bp + 256 + ko);
    acc = __builtin_amdgcn_mfma_f32_16x16x32_bf16(a, b, acc, 0, 0, 0);
  }
  if(mo < 9){
    #pragma unroll
    for(int r=0; r<4; r++){
      int b = blockIdx.x*64 + w*16 + (l>>4)*4 + r;
      out[((size_t)b*9 + mo)*8 + j] = (acc[r] + ((j==0) ? b3l[mo] : 0.f)) * INV_SQRT2F;
    }
  }
}

// ---------------- launch ----------------
extern "C" void kernel_launch(void* const* d_in, const int* in_sizes, int n_in,
                              void* d_out, int out_size, void* d_ws, size_t ws_size,
                              hipStream_t stream){
  const float* x        = (const float*)d_in[0];
  const float* w_right1 = (const float*)d_in[1];
  const float* norm_a1  = (const float*)d_in[2];
  const float* w_left1  = (const float*)d_in[3];
  const float* b_left1  = (const float*)d_in[4];
  const float* gp_w1    = (const float*)d_in[5];
  const float* silu_a   = (const float*)d_in[6];
  const float* silu_b   = (const float*)d_in[7];
  const float* w_right2 = (const float*)d_in[8];
  const float* norm_a2  = (const float*)d_in[9];
  const float* w_left2  = (const float*)d_in[10];
  const float* b_left2  = (const float*)d_in[11];
  const float* gp_w2    = (const float*)d_in[12];
  const float* w_right3 = (const float*)d_in[13];
  const float* norm_a3  = (const float*)d_in[14];
  const float* w_left3  = (const float*)d_in[15];
  const float* b_left3  = (const float*)d_in[16];
  const float* gp_w3    = (const float*)d_in[17];
  float* out = (float*)d_out;

  char* wsb = (char*)d_ws;
  __hip_bfloat16* xP    = (__hip_bfloat16*)wsb;
  __hip_bfloat16* xrI   = (__hip_bfloat16*)wsb;
  __hip_bfloat16* pairP = (__hip_bfloat16*)wsb;
  float*          linr2 = (float*)(wsb + 16777216);
  float*          left2 = (float*)(wsb + 20971520);
  float*          h2f   = (float*)(wsb + 25165824);
  __hip_bfloat16* h2P   = (__hip_bfloat16*)(wsb + 29360128);
  __hip_bfloat16* wP    = (__hip_bfloat16*)(wsb + 33554432);
  __hip_bfloat16* h1P   = (__hip_bfloat16*)(wsb + 33554432);
  float*          h1s   = (float*)(wsb + 35651584);
  __hip_bfloat16* linrP = (__hip_bfloat16*)(wsb + 41943040);
  float*          h1part= (float*)(wsb + 41943040);
  float*          linr3 = (float*)(wsb + 41943040);
  __hip_bfloat16* Bpack = (__hip_bfloat16*)(wsb + 75497472);
  __hip_bfloat16* wlP   = (__hip_bfloat16*)(wsb + 77594624);
  float*          leftB = (float*)(wsb + 77856768);
  __hip_bfloat16* w2rP  = (__hip_bfloat16*)(wsb + 82051072);
  __hip_bfloat16* w2lP  = (__hip_bfloat16*)(wsb + 82051072 + 16384);
  __hip_bfloat16* w3rP  = (__hip_bfloat16*)(wsb + 82051072 + 32768);
  __hip_bfloat16* Bp3   = (__hip_bfloat16*)(wsb + 82051072 + 49152);

  pack_x<<<8192, 256, 0, stream>>>(x, xP);
  pack_misc<<<2288, 256, 0, stream>>>(w_right1, gp_w1, w_left1,
                                      w_right2, w_left2, w_right3, gp_w3, w_left3,
                                      wP, Bpack, wlP, w2rP, w2lP, w3rP, Bp3);
  k1_mfma<<<dim3(32, 4, 8), 256, 0, stream>>>(xP, wP, linrP);
  k_left<<<dim3(64, 8), 256, 0, stream>>>(xP, wlP, leftB);
  knorm<<<1024, 256, 0, stream>>>(linrP, norm_a1, xrI);
  k2_mfma<<<dim3(64, 8), 256, 0, stream>>>(x, xrI, Bpack, h1part);
  k2b_silu<<<512, 256, 0, stream>>>(h1part, leftB, b_left1, silu_a, silu_b, h1s, h1P);
  k3a<<<dim3(64, 8), 256, 0, stream>>>(h1P, w2rP, w2lP, linr2, left2);
  k3b<<<512, 256, 0, stream>>>(linr2, left2, h1s, norm_a2, gp_w2, b_left2,
                               silu_a, silu_b, h2f, h2P);
  k3c<<<dim3(64, 8), 256, 0, stream>>>(h2P, w3rP, linr3);
  k3d<<<512, 256, 0, stream>>>(linr3, h2f, norm_a3, pairP);
  k3e<<<dim3(64, 8), 256, 0, stream>>>(pairP, h2P, Bp3, b_left3, out);
}

// Round 10
// 169.037 us; speedup vs baseline: 1.0195x; 1.0195x over previous
//
#include <hip/hip_runtime.h>
#include <hip/hip_bf16.h>
#include <math.h>

#define INV_SQRT2F 0.70710678118654752440f
#define AS1 __attribute__((address_space(1)))
#define AS3 __attribute__((address_space(3)))

typedef __attribute__((ext_vector_type(8))) short short8;
typedef __attribute__((ext_vector_type(4))) float floatx4;

// ---------------- compile-time algebra tables ----------------
struct Tables {
  int   kof[8][8];
  float cs[8][8];
  int   widx[8][8];
};
constexpr int t_bm(int i){ constexpr int t[8] = {0,1,2,4,3,5,6,7}; return t[i]; }
constexpr int t_idx(int b){ constexpr int t[8] = {0,1,2,4,3,5,6,7}; return t[b]; }
constexpr int t_gr(int i){ constexpr int t[8] = {0,1,1,1,2,2,2,3}; return t[i]; }
constexpr int t_pc(int x){ int c=0; while(x){ c += x&1; x >>= 1; } return c; }
constexpr float t_sign(int a, int b){
  float s = 1.f; int aa = a >> 1;
  while(aa){ if(t_pc(aa & b) & 1) s = -s; aa >>= 1; }
  return s;
}
constexpr int   c_kof(int j,int i){ return t_idx(t_bm(i)^t_bm(j)); }
constexpr float c_cs(int j,int i){ return t_sign(t_bm(i), t_bm(c_kof(j,i))); }
constexpr int   c_widx(int j,int i){ return t_gr(i)*16 + t_gr(j)*4 + t_gr(c_kof(j,i)); }
constexpr Tables mkTables(){
  Tables T{};
  for(int j=0;j<8;j++) for(int i=0;i<8;i++){
    T.kof[j][i]  = c_kof(j,i);
    T.cs[j][i]   = c_cs(j,i);
    T.widx[j][i] = c_widx(j,i);
  }
  return T;
}
__device__ const Tables d_TB = mkTables();

__device__ __forceinline__ float rcpf(float v){ return __builtin_amdgcn_rcpf(v); }
__device__ __forceinline__ float sigf(float z){ return rcpf(1.f + __expf(-z)); }
__device__ __forceinline__ int gradeOfIdx(int i){ return (i==0)?0:((i<4)?1:((i<7)?2:3)); }
__device__ __forceinline__ short f2bf(float v){
  __hip_bfloat16 h = __float2bfloat16(v);
  short s; __builtin_memcpy(&s, &h, 2); return s;
}
__device__ __forceinline__ float bf2f(short s){
  unsigned int w = ((unsigned int)(unsigned short)s) << 16;
  float f; __builtin_memcpy(&f, &w, 4); return f;
}
__device__ __forceinline__ void norm8v(float* v, float4 na){
  float s0 = sigf(na.x)*(fabsf(v[0])-1.f)+1.f+1e-6f;
  float s1 = sigf(na.y)*(sqrtf(v[1]*v[1]+v[2]*v[2]+v[3]*v[3])-1.f)+1.f+1e-6f;
  float s2 = sigf(na.z)*(sqrtf(v[4]*v[4]+v[5]*v[5]+v[6]*v[6])-1.f)+1.f+1e-6f;
  float s3 = sigf(na.w)*(fabsf(v[7])-1.f)+1.f+1e-6f;
  float r0 = rcpf(s0), r1 = rcpf(s1), r2 = rcpf(s2), r3 = rcpf(s3);
  v[0]*=r0; v[1]*=r1; v[2]*=r1; v[3]*=r1; v[4]*=r2; v[5]*=r2; v[6]*=r2; v[7]*=r3;
}

// ---------------- pack_x: x fp32 [b][m][8] -> 8 bf16 planes [i][b*512+m] ----------------
__global__ __launch_bounds__(256) void pack_x(const float* __restrict__ x,
                                              __hip_bfloat16* __restrict__ xP){
  size_t e = (size_t)blockIdx.x*256 + threadIdx.x;
  float4 u0 = *(const float4*)(x + e*8);
  float4 u1 = *(const float4*)(x + e*8 + 4);
  float u[8] = {u0.x,u0.y,u0.z,u0.w,u1.x,u1.y,u1.z,u1.w};
  #pragma unroll
  for(int i=0;i<8;i++) xP[(size_t)i*2097152 + e] = __float2bfloat16(u[i]);
}

// ---------------- pack_misc: fused small weight packs ----------------
__global__ __launch_bounds__(256) void pack_misc(const float* __restrict__ w,
                                                 const float* __restrict__ gpw,
                                                 const float* __restrict__ wl,
                                                 const float* __restrict__ w2r,
                                                 const float* __restrict__ w2l,
                                                 const float* __restrict__ w3r,
                                                 const float* __restrict__ gw3,
                                                 const float* __restrict__ w3l,
                                                 __hip_bfloat16* __restrict__ wP,
                                                 __hip_bfloat16* __restrict__ Bpack,
                                                 __hip_bfloat16* __restrict__ wlP,
                                                 __hip_bfloat16* __restrict__ w2rP,
                                                 __hip_bfloat16* __restrict__ w2lP,
                                                 __hip_bfloat16* __restrict__ w3rP,
                                                 __hip_bfloat16* __restrict__ Bp3){
  const int bx = blockIdx.x;
  if(bx < 1024){
    size_t e = (size_t)bx*256 + threadIdx.x;
    float4 u = *(const float4*)(w + e*4);
    float v[4] = {u.x,u.y,u.z,u.w};
    #pragma unroll
    for(int g=0; g<4; g++) wP[(size_t)g*262144 + e] = __float2bfloat16(v[g]);
  } else if(bx < 1536){
    int t = (bx-1024)*256 + threadIdx.x;          // j*16384 + n*32 + m
    int j = t >> 14; int n = (t >> 5) & 511; int m = t & 31;
    const float* src = gpw + ((size_t)m*512 + n)*64;
    short8 o;
    #pragma unroll
    for(int jj=0; jj<8; jj++){
      if(jj == j){
        #pragma unroll
        for(int i=0;i<8;i++) o[i] = f2bf(c_cs(jj,i) * src[c_widx(jj,i)]);
      }
    }
    int q = n & 3;
    *(short8*)(Bpack + (size_t)(n>>2)*8192 + j*1024 + q*256 + m*8) = o;
  } else if(bx < 2048){
    int t2 = (bx-1536)*256 + threadIdx.x;         // j*16384 + m*512 + n
    int j = t2 >> 14; int m = (t2 >> 9) & 31; int n = t2 & 511;
    int g = gradeOfIdx(j);
    wlP[t2] = __float2bfloat16(wl[((size_t)m*512 + n)*4 + g]);
  } else if(bx < 2144){
    int t = (bx-2048)*256 + threadIdx.x;
    int which = t >> 13; int r = t & 8191;
    int j = r >> 10; int n = (r >> 5) & 31; int m = r & 31;
    int g = gradeOfIdx(j);
    const float* src = (which==0) ? w2r : (which==1) ? w2l : w3r;
    __hip_bfloat16* dst = (which==0) ? w2rP : (which==1) ? w2lP : w3rP;
    dst[r] = __float2bfloat16(src[((size_t)n*32 + m)*4 + g]);
  } else {
    int t2 = (bx-2144)*256 + threadIdx.x;         // j*4608 + mo*288 + k
    if(t2 >= 36864) return;
    int j = t2 / 4608; int rem = t2 - j*4608;
    int mo = rem / 288; int k = rem - mo*288;
    float v = 0.f;
    if(mo < 9){
      if(k < 256){
        int n = k >> 3, i = k & 7;
        v = d_TB.cs[j][i] * gw3[((size_t)mo*32 + n)*64 + d_TB.widx[j][i]];
      } else {
        int n = k - 256;
        v = w3l[((size_t)mo*32 + n)*4 + gradeOfIdx(j)];
      }
    }
    Bp3[t2] = __float2bfloat16(v);
  }
}

// ---------------- K1 MFMA: linrP[i][b][n] = sum_m xP[i][b][m] * wP[g(i)][n][m] ----------------
// BM=128, BN=128, BK=64; grid (32,4,8)
__global__ __launch_bounds__(256) void k1_mfma(const __hip_bfloat16* __restrict__ xP,
                                               const __hip_bfloat16* __restrict__ wP,
                                               __hip_bfloat16* __restrict__ linrP){
  __shared__ __align__(16) char lds[32768];
  char* As = lds;
  char* Bs = lds + 16384;
  const int tid = threadIdx.x;
  const int l   = tid & 63;
  const int w   = tid >> 6;
  const int i   = blockIdx.z;
  const int g   = gradeOfIdx(i);
  const size_t b0 = (size_t)blockIdx.x * 128;
  const size_t n0 = (size_t)blockIdx.y * 128;
  const __hip_bfloat16* Ag = xP + (size_t)i*2097152;
  const __hip_bfloat16* Bg = wP + (size_t)g*262144;

  const int wave_m = (w & 1) * 64;
  const int wave_n = (w >> 1) * 64;
  const int srow = l >> 3;
  const int scol = ((l & 7) ^ srow) * 8;

  floatx4 acc[4][4] = {};

  for(int kt = 0; kt < 512; kt += 64){
    #pragma unroll
    for(int it=0; it<4; it++){
      int c   = it*4 + w;
      int row = c*8 + srow;
      const __hip_bfloat16* sa = Ag + (b0 + row)*512 + kt + scol;
      const __hip_bfloat16* sb = Bg + (n0 + row)*512 + kt + scol;
      __builtin_amdgcn_global_load_lds((const AS1 void*)sa, (AS3 void*)(As + c*1024 + l*16), 16, 0, 0);
      __builtin_amdgcn_global_load_lds((const AS1 void*)sb, (AS3 void*)(Bs + c*1024 + l*16), 16, 0, 0);
    }
    __syncthreads();
    #pragma unroll
    for(int ks=0; ks<2; ks++){
      short8 af[4], bf[4];
      #pragma unroll
      for(int f=0; f<4; f++){
        int rA = wave_m + f*16 + (l & 15);
        int ca = (ks*64 + (l>>4)*16) ^ ((rA & 7) << 4);
        af[f] = *(const short8*)(As + rA*128 + ca);
        int rB = wave_n + f*16 + (l & 15);
        int cb = (ks*64 + (l>>4)*16) ^ ((rB & 7) << 4);
        bf[f] = *(const short8*)(Bs + rB*128 + cb);
      }
      #pragma unroll
      for(int mf=0; mf<4; mf++){
        #pragma unroll
        for(int nf=0; nf<4; nf++){
          acc[mf][nf] = __builtin_amdgcn_mfma_f32_16x16x32_bf16(af[mf], bf[nf], acc[mf][nf], 0, 0, 0);
        }
      }
    }
    __syncthreads();
  }
  __hip_bfloat16* outp = linrP + (size_t)i*2097152;
  #pragma unroll
  for(int mf=0; mf<4; mf++){
    #pragma unroll
    for(int nf=0; nf<4; nf++){
      #pragma unroll
      for(int r=0; r<4; r++){
        size_t m = wave_m + mf*16 + ((l>>4)<<2) + r;
        size_t n = wave_n + nf*16 + (l & 15);
        outp[(b0+m)*512 + n0+n] = __float2bfloat16(acc[mf][nf][r]);
      }
    }
  }
}

// ---------------- k_left: leftB[j][b][m] = sum_n xP[j][b][n]*wlP[j][m][n]  (MFMA) ----------------
__global__ __launch_bounds__(256) void k_left(const __hip_bfloat16* __restrict__ xP,
                                              const __hip_bfloat16* __restrict__ wlP,
                                              float* __restrict__ leftB){
  const int tid = threadIdx.x;
  const int l = tid & 63, w = tid >> 6;
  const int j = blockIdx.y;
  const int row = blockIdx.x*64 + w*16 + (l & 15);
  floatx4 acc[2] = {};
  const __hip_bfloat16* Ap = xP + (size_t)j*2097152;
  const __hip_bfloat16* Wp = wlP + (size_t)j*16384;
  for(int nc=0; nc<16; nc++){
    int nb = nc*32 + (l>>4)*8;
    short8 a  = *(const short8*)(Ap + (size_t)row*512 + nb);
    short8 b0 = *(const short8*)(Wp + (l&15)*512 + nb);
    short8 b1 = *(const short8*)(Wp + ((l&15)+16)*512 + nb);
    acc[0] = __builtin_amdgcn_mfma_f32_16x16x32_bf16(a, b0, acc[0], 0, 0, 0);
    acc[1] = __builtin_amdgcn_mfma_f32_16x16x32_bf16(a, b1, acc[1], 0, 0, 0);
  }
  #pragma unroll
  for(int mf=0; mf<2; mf++){
    #pragma unroll
    for(int r=0; r<4; r++){
      int b = blockIdx.x*64 + w*16 + (l>>4)*4 + r;
      leftB[(size_t)j*131072 + b*32 + mf*16 + (l&15)] = acc[mf][r];
    }
  }
}

// ---------------- knorm: normalize linrP planes -> xrI interleaved bf16 [e][k] ----------------
__global__ __launch_bounds__(256) void knorm(const __hip_bfloat16* __restrict__ linrP,
                                             const float* __restrict__ norm_a,
                                             __hip_bfloat16* __restrict__ xrI){
  const size_t base = ((size_t)blockIdx.x*256 + threadIdx.x) * 8;
  const short* lp = (const short*)linrP;
  short8 v[8];
  #pragma unroll
  for(int i=0;i<8;i++) v[i] = *(const short8*)(lp + (size_t)i*2097152 + base);
  short8 o[8];
  #pragma unroll
  for(int s=0;s<8;s++){
    float u[8];
    #pragma unroll
    for(int i=0;i<8;i++) u[i] = bf2f(v[i][s]);
    int n = (int)((base + s) & 511);
    float4 na = *(const float4*)(norm_a + n*4);
    norm8v(u, na);
    #pragma unroll
    for(int i=0;i<8;i++) o[s][i] = f2bf(u[i]);
  }
  short* op = (short*)xrI;
  #pragma unroll
  for(int s=0;s<8;s++) *(short8*)(op + (base+s)*8) = o[s];
}

// ---------------- k2_mfma: fcgp1 product via per-j register-built A fragments (R6 config) ----------------
// Bpack layout: [n>>2][j][q][m][i] — 16KB contiguous per 4-n group.
__global__ __launch_bounds__(256) void k2_mfma(const float* __restrict__ x,
                                               const __hip_bfloat16* __restrict__ xrI,
                                               const __hip_bfloat16* __restrict__ Bpack,
                                               float* __restrict__ h1part){
  const int tid = threadIdx.x;
  const int l = tid & 63, w = tid >> 6;
  const int row = blockIdx.x*64 + w*16 + (l & 15);
  const int nsb = blockIdx.y * 64;
  const int boff = (l>>4)*256 + (l&15)*8;
  floatx4 acc[8][2] = {};

  for(int nc = 0; nc < 16; nc++){
    const int n = nsb + nc*4 + (l>>4);
    const size_t e = (size_t)row*512 + n;
    float4 xa = *(const float4*)(x + e*8);
    float4 xb = *(const float4*)(x + e*8 + 4);
    float xv[8] = {xa.x,xa.y,xa.z,xa.w,xb.x,xb.y,xb.z,xb.w};
    short8 xri = *(const short8*)((const short*)xrI + e*8);
    float xr[8];
    #pragma unroll
    for(int i=0;i<8;i++) xr[i] = bf2f(xri[i]);
    const __hip_bfloat16* bp_nc = Bpack + (size_t)(blockIdx.y*16 + nc)*8192 + boff;
    #pragma unroll
    for(int j=0;j<8;j++){
      short8 af;
      #pragma unroll
      for(int i=0;i<8;i++) af[i] = f2bf(xv[i] * xr[c_kof(j,i)]);
      short8 b0 = *(const short8*)(bp_nc + j*1024);
      short8 b1 = *(const short8*)(bp_nc + j*1024 + 128);
      acc[j][0] = __builtin_amdgcn_mfma_f32_16x16x32_bf16(af, b0, acc[j][0], 0, 0, 0);
      acc[j][1] = __builtin_amdgcn_mfma_f32_16x16x32_bf16(af, b1, acc[j][1], 0, 0, 0);
    }
  }
  const int sp = blockIdx.y;
  #pragma unroll
  for(int j=0;j<8;j++){
    #pragma unroll
    for(int mf=0; mf<2; mf++){
      #pragma unroll
      for(int r=0; r<4; r++){
        int b = blockIdx.x*64 + w*16 + (l>>4)*4 + r;
        h1part[((size_t)(sp*8+j))*131072 + b*32 + mf*16 + (l&15)] = acc[j][mf][r];
      }
    }
  }
}

// ---------------- K2b: reduce + left + bias + silu -> h1s f32 + h1P bf16 planes ----------------
__global__ __launch_bounds__(256) void k2b_silu(const float* __restrict__ h1part,
                                                const float* __restrict__ leftB,
                                                const float* __restrict__ bl,
                                                const float* __restrict__ sa,
                                                const float* __restrict__ sb,
                                                float* __restrict__ h1s,
                                                __hip_bfloat16* __restrict__ h1P){
  int idx = blockIdx.x*256 + threadIdx.x;  // b*32+m
  int m = idx & 31;
  float v[8];
  #pragma unroll
  for(int j=0;j<8;j++){
    float s = leftB[(size_t)j*131072 + idx];
    #pragma unroll
    for(int sp=0; sp<8; sp++) s += h1part[((size_t)(sp*8+j))*131072 + idx];
    v[j] = s;
  }
  v[0] += bl[m];
  #pragma unroll
  for(int i=0;i<8;i++) v[i] *= INV_SQRT2F;
  float q1 = v[1]*v[1]+v[2]*v[2]+v[3]*v[3];
  float q2 = v[4]*v[4]+v[5]*v[5]+v[6]*v[6];
  float q3 = v[7]*v[7];
  float4 sa4 = *(const float4*)&sa[m*4];
  float4 sb4 = *(const float4*)&sb[m*4];
  float g0 = sigf(sa4.x*v[0] + sb4.x);
  float g1 = sigf(sa4.y*q1   + sb4.y);
  float g2 = sigf(sa4.z*q2   + sb4.z);
  float g3 = sigf(sa4.w*q3   + sb4.w);
  float o[8] = {g0*v[0], g1*v[1], g1*v[2], g1*v[3], g2*v[4], g2*v[5], g2*v[6], g3*v[7]};
  *(float4*)&h1s[(size_t)idx*8]     = make_float4(o[0],o[1],o[2],o[3]);
  *(float4*)&h1s[(size_t)idx*8 + 4] = make_float4(o[4],o[5],o[6],o[7]);
  #pragma unroll
  for(int j=0;j<8;j++) h1P[(size_t)j*131072 + idx] = __float2bfloat16(o[j]);
}

// ---------------- k3ab: fused lin_r2/left2 MFMA (j-loop) + norm + sgp + silu ----------------
// grid: 64 blocks. Each lane ends with all 8 j for its 8 output sites in registers.
__global__ __launch_bounds__(256) void k3ab(const __hip_bfloat16* __restrict__ h1P,
                                            const __hip_bfloat16* __restrict__ w2rP,
                                            const __hip_bfloat16* __restrict__ w2lP,
                                            const float* __restrict__ h1s,
                                            const float* __restrict__ na2,
                                            const float* __restrict__ gw2,
                                            const float* __restrict__ b2l,
                                            const float* __restrict__ sa,
                                            const float* __restrict__ sb,
                                            float* __restrict__ h2f,
                                            __hip_bfloat16* __restrict__ h2P){
  const int tid = threadIdx.x;
  const int l = tid & 63, w = tid >> 6;
  const int row = blockIdx.x*64 + w*16 + (l & 15);
  const int ko = (l>>4)*8;
  floatx4 xacc[8][2], lacc[8][2];
  #pragma unroll
  for(int j=0;j<8;j++){
    short8 a   = *(const short8*)(h1P + (size_t)j*131072 + (size_t)row*32 + ko);
    short8 br0 = *(const short8*)(w2rP + j*1024 + (l&15)*32 + ko);
    short8 br1 = *(const short8*)(w2rP + j*1024 + ((l&15)+16)*32 + ko);
    short8 bl0 = *(const short8*)(w2lP + j*1024 + (l&15)*32 + ko);
    short8 bl1 = *(const short8*)(w2lP + j*1024 + ((l&15)+16)*32 + ko);
    floatx4 z0 = {}, z1 = {}, z2 = {}, z3 = {};
    xacc[j][0] = __builtin_amdgcn_mfma_f32_16x16x32_bf16(a, br0, z0, 0, 0, 0);
    xacc[j][1] = __builtin_amdgcn_mfma_f32_16x16x32_bf16(a, br1, z1, 0, 0, 0);
    lacc[j][0] = __builtin_amdgcn_mfma_f32_16x16x32_bf16(a, bl0, z2, 0, 0, 0);
    lacc[j][1] = __builtin_amdgcn_mfma_f32_16x16x32_bf16(a, bl1, z3, 0, 0, 0);
  }
  #pragma unroll
  for(int h=0; h<2; h++){
    #pragma unroll
    for(int r=0; r<4; r++){
      int b = blockIdx.x*64 + w*16 + (l>>4)*4 + r;
      int n = h*16 + (l & 15);
      size_t idx = (size_t)b*32 + n;
      float x2[8], lf[8];
      #pragma unroll
      for(int j=0;j<8;j++){ x2[j] = xacc[j][h][r]; lf[j] = lacc[j][h][r]; }
      norm8v(x2, *(const float4*)&na2[n*4]);
      float4 h0 = *(const float4*)&h1s[idx*8];
      float4 h1v = *(const float4*)&h1s[idx*8 + 4];
      float hh[8] = {h0.x,h0.y,h0.z,h0.w,h1v.x,h1v.y,h1v.z,h1v.w};
      const float* g2 = gw2 + (size_t)n*64;
      float v[8];
      #pragma unroll
      for(int j=0;j<8;j++){
        float pr = 0.f;
        #pragma unroll
        for(int i=0;i<8;i++)
          pr = fmaf(c_cs(j,i) * hh[i] * x2[c_kof(j,i)], g2[c_widx(j,i)], pr);
        v[j] = (pr + lf[j] + ((j==0) ? b2l[n] : 0.f)) * INV_SQRT2F;
      }
      float q1 = v[1]*v[1]+v[2]*v[2]+v[3]*v[3];
      float q2 = v[4]*v[4]+v[5]*v[5]+v[6]*v[6];
      float q3 = v[7]*v[7];
      float4 sa4 = *(const float4*)&sa[n*4];
      float4 sb4 = *(const float4*)&sb[n*4];
      float g0 = sigf(sa4.x*v[0] + sb4.x);
      float g1 = sigf(sa4.y*q1   + sb4.y);
      float gg2 = sigf(sa4.z*q2  + sb4.z);
      float g3 = sigf(sa4.w*q3   + sb4.w);
      float o[8] = {g0*v[0], g1*v[1], g1*v[2], g1*v[3], gg2*v[4], gg2*v[5], gg2*v[6], g3*v[7]};
      *(float4*)&h2f[idx*8]     = make_float4(o[0],o[1],o[2],o[3]);
      *(float4*)&h2f[idx*8 + 4] = make_float4(o[4],o[5],o[6],o[7]);
      #pragma unroll
      for(int j=0;j<8;j++) h2P[(size_t)j*131072 + idx] = __float2bfloat16(o[j]);
    }
  }
}

// ---------------- k3cd: fused lin_r3 MFMA (j-loop) + norm + pair build ----------------
__global__ __launch_bounds__(256) void k3cd(const __hip_bfloat16* __restrict__ h2P,
                                            const __hip_bfloat16* __restrict__ w3rP,
                                            const float* __restrict__ h2f,
                                            const float* __restrict__ na3,
                                            __hip_bfloat16* __restrict__ pairP){
  const int tid = threadIdx.x;
  const int l = tid & 63, w = tid >> 6;
  const int row = blockIdx.x*64 + w*16 + (l & 15);
  const int ko = (l>>4)*8;
  floatx4 xacc[8][2];
  #pragma unroll
  for(int j=0;j<8;j++){
    short8 a  = *(const short8*)(h2P + (size_t)j*131072 + (size_t)row*32 + ko);
    short8 b0 = *(const short8*)(w3rP + j*1024 + (l&15)*32 + ko);
    short8 b1 = *(const short8*)(w3rP + j*1024 + ((l&15)+16)*32 + ko);
    floatx4 z0 = {}, z1 = {};
    xacc[j][0] = __builtin_amdgcn_mfma_f32_16x16x32_bf16(a, b0, z0, 0, 0, 0);
    xacc[j][1] = __builtin_amdgcn_mfma_f32_16x16x32_bf16(a, b1, z1, 0, 0, 0);
  }
  #pragma unroll
  for(int h=0; h<2; h++){
    #pragma unroll
    for(int r=0; r<4; r++){
      int b = blockIdx.x*64 + w*16 + (l>>4)*4 + r;
      int n = h*16 + (l & 15);
      size_t idx = (size_t)b*32 + n;
      float x3[8];
      #pragma unroll
      for(int j=0;j<8;j++) x3[j] = xacc[j][h][r];
      norm8v(x3, *(const float4*)&na3[n*4]);
      float4 h0 = *(const float4*)&h2f[idx*8];
      float4 h1v = *(const float4*)&h2f[idx*8 + 4];
      float hh[8] = {h0.x,h0.y,h0.z,h0.w,h1v.x,h1v.y,h1v.z,h1v.w};
      #pragma unroll
      for(int j=0;j<8;j++){
        short8 o;
        #pragma unroll
        for(int i=0;i<8;i++) o[i] = f2bf(hh[i] * x3[c_kof(j,i)]);
        *(short8*)(pairP + (size_t)j*1048576 + idx*8) = o;
      }
    }
  }
}

// ---------------- k3e: out[b][mo][j] = (sum_k pair/h2 x Bp3 + bias) * c ----------------
__global__ __launch_bounds__(256) void k3e(const __hip_bfloat16* __restrict__ pairP,
                                           const __hip_bfloat16* __restrict__ h2P,
                                           const __hip_bfloat16* __restrict__ Bp3,
                                           const float* __restrict__ b3l,
                                           float* __restrict__ out){
  const int tid = threadIdx.x;
  const int l = tid & 63, w = tid >> 6;
  const int j = blockIdx.y;
  const int row = blockIdx.x*64 + w*16 + (l & 15);
  const int mo = l & 15;
  const int ko = (l>>4)*8;
  floatx4 acc = {};
  const __hip_bfloat16* Ap = pairP + (size_t)j*1048576 + (size_t)row*256;
  const __hip_bfloat16* Bp = Bp3 + (size_t)j*4608 + mo*288;
  #pragma unroll
  for(int kc=0; kc<8; kc++){
    short8 a = *(const short8*)(Ap + kc*32 + ko);
    short8 b = *(const short8*)(Bp + kc*32 + ko);
    acc = __builtin_amdgcn_mfma_f32_16x16x32_bf16(a, b, acc, 0, 0, 0);
  }
  {
    short8 a = *(const short8*)(h2P + (size_t)j*131072 + (size_t)row*32 + ko);
    short8 b = *(const short8*)(Bp + 256 + ko);
    acc = __builtin_amdgcn_mfma_f32_16x16x32_bf16(a, b, acc, 0, 0, 0);
  }
  if(mo < 9){
    #pragma unroll
    for(int r=0; r<4; r++){
      int b = blockIdx.x*64 + w*16 + (l>>4)*4 + r;
      out[((size_t)b*9 + mo)*8 + j] = (acc[r] + ((j==0) ? b3l[mo] : 0.f)) * INV_SQRT2F;
    }
  }
}

// ---------------- launch ----------------
extern "C" void kernel_launch(void* const* d_in, const int* in_sizes, int n_in,
                              void* d_out, int out_size, void* d_ws, size_t ws_size,
                              hipStream_t stream){
  const float* x        = (const float*)d_in[0];
  const float* w_right1 = (const float*)d_in[1];
  const float* norm_a1  = (const float*)d_in[2];
  const float* w_left1  = (const float*)d_in[3];
  const float* b_left1  = (const float*)d_in[4];
  const float* gp_w1    = (const float*)d_in[5];
  const float* silu_a   = (const float*)d_in[6];
  const float* silu_b   = (const float*)d_in[7];
  const float* w_right2 = (const float*)d_in[8];
  const float* norm_a2  = (const float*)d_in[9];
  const float* w_left2  = (const float*)d_in[10];
  const float* b_left2  = (const float*)d_in[11];
  const float* gp_w2    = (const float*)d_in[12];
  const float* w_right3 = (const float*)d_in[13];
  const float* norm_a3  = (const float*)d_in[14];
  const float* w_left3  = (const float*)d_in[15];
  const float* b_left3  = (const float*)d_in[16];
  const float* gp_w3    = (const float*)d_in[17];
  float* out = (float*)d_out;

  char* wsb = (char*)d_ws;
  // ws layout (peak ~82.2 MB):
  //  [0,32M):   xP (pack_x..k_left) -> xrI (knorm..k2) -> pairP(16M)@0;
  //             h2f @25,165,824 (4M)  h2P @29,360,128 (2M)
  //  [32M,34M): wP (dead after k1) -> h1P bf16 [8][131072]
  //  [35,651,584, 39,845,888): h1s f32
  //  [41,943,040, 75,497,472): linrP (dead after knorm) -> h1part f32 [64][131072]
  //  [75,497,472,...): Bpack(2M), wlP(0.25M), leftB(4M), small tail packs
  __hip_bfloat16* xP    = (__hip_bfloat16*)wsb;
  __hip_bfloat16* xrI   = (__hip_bfloat16*)wsb;
  __hip_bfloat16* pairP = (__hip_bfloat16*)wsb;
  float*          h2f   = (float*)(wsb + 25165824);
  __hip_bfloat16* h2P   = (__hip_bfloat16*)(wsb + 29360128);
  __hip_bfloat16* wP    = (__hip_bfloat16*)(wsb + 33554432);
  __hip_bfloat16* h1P   = (__hip_bfloat16*)(wsb + 33554432);
  float*          h1s   = (float*)(wsb + 35651584);
  __hip_bfloat16* linrP = (__hip_bfloat16*)(wsb + 41943040);
  float*          h1part= (float*)(wsb + 41943040);
  __hip_bfloat16* Bpack = (__hip_bfloat16*)(wsb + 75497472);
  __hip_bfloat16* wlP   = (__hip_bfloat16*)(wsb + 77594624);
  float*          leftB = (float*)(wsb + 77856768);
  __hip_bfloat16* w2rP  = (__hip_bfloat16*)(wsb + 82051072);
  __hip_bfloat16* w2lP  = (__hip_bfloat16*)(wsb + 82051072 + 16384);
  __hip_bfloat16* w3rP  = (__hip_bfloat16*)(wsb + 82051072 + 32768);
  __hip_bfloat16* Bp3   = (__hip_bfloat16*)(wsb + 82051072 + 49152);

  pack_x<<<8192, 256, 0, stream>>>(x, xP);
  pack_misc<<<2288, 256, 0, stream>>>(w_right1, gp_w1, w_left1,
                                      w_right2, w_left2, w_right3, gp_w3, w_left3,
                                      wP, Bpack, wlP, w2rP, w2lP, w3rP, Bp3);
  k1_mfma<<<dim3(32, 4, 8), 256, 0, stream>>>(xP, wP, linrP);
  k_left<<<dim3(64, 8), 256, 0, stream>>>(xP, wlP, leftB);
  knorm<<<1024, 256, 0, stream>>>(linrP, norm_a1, xrI);
  k2_mfma<<<dim3(64, 8), 256, 0, stream>>>(x, xrI, Bpack, h1part);
  k2b_silu<<<512, 256, 0, stream>>>(h1part, leftB, b_left1, silu_a, silu_b, h1s, h1P);
  k3ab<<<64, 256, 0, stream>>>(h1P, w2rP, w2lP, h1s, norm_a2, gp_w2, b_left2,
                               silu_a, silu_b, h2f, h2P);
  k3cd<<<64, 256, 0, stream>>>(h2P, w3rP, h2f, norm_a3, pairP);
  k3e<<<dim3(64, 8), 256, 0, stream>>>(pairP, h2P, Bp3, b_left3, out);
}

// Round 11
// 150.989 us; speedup vs baseline: 1.1414x; 1.1195x over previous
//
#include <hip/hip_runtime.h>
#include <hip/hip_bf16.h>
#include <math.h>

#define INV_SQRT2F 0.70710678118654752440f
#define AS1 __attribute__((address_space(1)))
#define AS3 __attribute__((address_space(3)))

typedef __attribute__((ext_vector_type(8))) short short8;
typedef __attribute__((ext_vector_type(4))) float floatx4;

// ---------------- compile-time algebra tables ----------------
struct Tables {
  int   kof[8][8];
  float cs[8][8];
  int   widx[8][8];
};
constexpr int t_bm(int i){ constexpr int t[8] = {0,1,2,4,3,5,6,7}; return t[i]; }
constexpr int t_idx(int b){ constexpr int t[8] = {0,1,2,4,3,5,6,7}; return t[b]; }
constexpr int t_gr(int i){ constexpr int t[8] = {0,1,1,1,2,2,2,3}; return t[i]; }
constexpr int t_pc(int x){ int c=0; while(x){ c += x&1; x >>= 1; } return c; }
constexpr float t_sign(int a, int b){
  float s = 1.f; int aa = a >> 1;
  while(aa){ if(t_pc(aa & b) & 1) s = -s; aa >>= 1; }
  return s;
}
constexpr int   c_kof(int j,int i){ return t_idx(t_bm(i)^t_bm(j)); }
constexpr float c_cs(int j,int i){ return t_sign(t_bm(i), t_bm(c_kof(j,i))); }
constexpr int   c_widx(int j,int i){ return t_gr(i)*16 + t_gr(j)*4 + t_gr(c_kof(j,i)); }
constexpr Tables mkTables(){
  Tables T{};
  for(int j=0;j<8;j++) for(int i=0;i<8;i++){
    T.kof[j][i]  = c_kof(j,i);
    T.cs[j][i]   = c_cs(j,i);
    T.widx[j][i] = c_widx(j,i);
  }
  return T;
}
__device__ const Tables d_TB = mkTables();

__device__ __forceinline__ float rcpf(float v){ return __builtin_amdgcn_rcpf(v); }
__device__ __forceinline__ float sigf(float z){ return rcpf(1.f + __expf(-z)); }
__device__ __forceinline__ int gradeOfIdx(int i){ return (i==0)?0:((i<4)?1:((i<7)?2:3)); }
__device__ __forceinline__ short f2bf(float v){
  __hip_bfloat16 h = __float2bfloat16(v);
  short s; __builtin_memcpy(&s, &h, 2); return s;
}
__device__ __forceinline__ float bf2f(short s){
  unsigned int w = ((unsigned int)(unsigned short)s) << 16;
  float f; __builtin_memcpy(&f, &w, 4); return f;
}
__device__ __forceinline__ void norm8v(float* v, float4 na){
  float s0 = sigf(na.x)*(fabsf(v[0])-1.f)+1.f+1e-6f;
  float s1 = sigf(na.y)*(sqrtf(v[1]*v[1]+v[2]*v[2]+v[3]*v[3])-1.f)+1.f+1e-6f;
  float s2 = sigf(na.z)*(sqrtf(v[4]*v[4]+v[5]*v[5]+v[6]*v[6])-1.f)+1.f+1e-6f;
  float s3 = sigf(na.w)*(fabsf(v[7])-1.f)+1.f+1e-6f;
  float r0 = rcpf(s0), r1 = rcpf(s1), r2 = rcpf(s2), r3 = rcpf(s3);
  v[0]*=r0; v[1]*=r1; v[2]*=r1; v[3]*=r1; v[4]*=r2; v[5]*=r2; v[6]*=r2; v[7]*=r3;
}

// ---------------- pack_x: x fp32 [b][m][8] -> 8 bf16 planes [i][b*512+m] ----------------
__global__ __launch_bounds__(256) void pack_x(const float* __restrict__ x,
                                              __hip_bfloat16* __restrict__ xP){
  size_t e = (size_t)blockIdx.x*256 + threadIdx.x;
  float4 u0 = *(const float4*)(x + e*8);
  float4 u1 = *(const float4*)(x + e*8 + 4);
  float u[8] = {u0.x,u0.y,u0.z,u0.w,u1.x,u1.y,u1.z,u1.w};
  #pragma unroll
  for(int i=0;i<8;i++) xP[(size_t)i*2097152 + e] = __float2bfloat16(u[i]);
}

// ---------------- pack_misc: fused small weight packs ----------------
__global__ __launch_bounds__(256) void pack_misc(const float* __restrict__ w,
                                                 const float* __restrict__ gpw,
                                                 const float* __restrict__ wl,
                                                 const float* __restrict__ w2r,
                                                 const float* __restrict__ w2l,
                                                 const float* __restrict__ w3r,
                                                 const float* __restrict__ gw3,
                                                 const float* __restrict__ w3l,
                                                 __hip_bfloat16* __restrict__ wP,
                                                 __hip_bfloat16* __restrict__ Bpack,
                                                 __hip_bfloat16* __restrict__ wlP,
                                                 __hip_bfloat16* __restrict__ w2rP,
                                                 __hip_bfloat16* __restrict__ w2lP,
                                                 __hip_bfloat16* __restrict__ w3rP,
                                                 __hip_bfloat16* __restrict__ Bp3){
  const int bx = blockIdx.x;
  if(bx < 1024){
    size_t e = (size_t)bx*256 + threadIdx.x;
    float4 u = *(const float4*)(w + e*4);
    float v[4] = {u.x,u.y,u.z,u.w};
    #pragma unroll
    for(int g=0; g<4; g++) wP[(size_t)g*262144 + e] = __float2bfloat16(v[g]);
  } else if(bx < 1536){
    int t = (bx-1024)*256 + threadIdx.x;          // j*16384 + n*32 + m
    int j = t >> 14; int n = (t >> 5) & 511; int m = t & 31;
    const float* src = gpw + ((size_t)m*512 + n)*64;
    short8 o;
    #pragma unroll
    for(int jj=0; jj<8; jj++){
      if(jj == j){
        #pragma unroll
        for(int i=0;i<8;i++) o[i] = f2bf(c_cs(jj,i) * src[c_widx(jj,i)]);
      }
    }
    int q = n & 3;
    *(short8*)(Bpack + (size_t)(n>>2)*8192 + j*1024 + q*256 + m*8) = o;
  } else if(bx < 2048){
    int t2 = (bx-1536)*256 + threadIdx.x;         // j*16384 + m*512 + n
    int j = t2 >> 14; int m = (t2 >> 9) & 31; int n = t2 & 511;
    int g = gradeOfIdx(j);
    wlP[t2] = __float2bfloat16(wl[((size_t)m*512 + n)*4 + g]);
  } else if(bx < 2144){
    int t = (bx-2048)*256 + threadIdx.x;
    int which = t >> 13; int r = t & 8191;
    int j = r >> 10; int n = (r >> 5) & 31; int m = r & 31;
    int g = gradeOfIdx(j);
    const float* src = (which==0) ? w2r : (which==1) ? w2l : w3r;
    __hip_bfloat16* dst = (which==0) ? w2rP : (which==1) ? w2lP : w3rP;
    dst[r] = __float2bfloat16(src[((size_t)n*32 + m)*4 + g]);
  } else {
    int t2 = (bx-2144)*256 + threadIdx.x;         // j*4608 + mo*288 + k
    if(t2 >= 36864) return;
    int j = t2 / 4608; int rem = t2 - j*4608;
    int mo = rem / 288; int k = rem - mo*288;
    float v = 0.f;
    if(mo < 9){
      if(k < 256){
        int n = k >> 3, i = k & 7;
        v = d_TB.cs[j][i] * gw3[((size_t)mo*32 + n)*64 + d_TB.widx[j][i]];
      } else {
        int n = k - 256;
        v = w3l[((size_t)mo*32 + n)*4 + gradeOfIdx(j)];
      }
    }
    Bp3[t2] = __float2bfloat16(v);
  }
}

// ---------------- K1 MFMA: linrP[i][b][n] = sum_m xP[i][b][m] * wP[g(i)][n][m] ----------------
// BM=128, BN=128, BK=64; grid (32,4,8)
__global__ __launch_bounds__(256) void k1_mfma(const __hip_bfloat16* __restrict__ xP,
                                               const __hip_bfloat16* __restrict__ wP,
                                               __hip_bfloat16* __restrict__ linrP){
  __shared__ __align__(16) char lds[32768];
  char* As = lds;
  char* Bs = lds + 16384;
  const int tid = threadIdx.x;
  const int l   = tid & 63;
  const int w   = tid >> 6;
  const int i   = blockIdx.z;
  const int g   = gradeOfIdx(i);
  const size_t b0 = (size_t)blockIdx.x * 128;
  const size_t n0 = (size_t)blockIdx.y * 128;
  const __hip_bfloat16* Ag = xP + (size_t)i*2097152;
  const __hip_bfloat16* Bg = wP + (size_t)g*262144;

  const int wave_m = (w & 1) * 64;
  const int wave_n = (w >> 1) * 64;
  const int srow = l >> 3;
  const int scol = ((l & 7) ^ srow) * 8;

  floatx4 acc[4][4] = {};

  for(int kt = 0; kt < 512; kt += 64){
    #pragma unroll
    for(int it=0; it<4; it++){
      int c   = it*4 + w;
      int row = c*8 + srow;
      const __hip_bfloat16* sa = Ag + (b0 + row)*512 + kt + scol;
      const __hip_bfloat16* sb = Bg + (n0 + row)*512 + kt + scol;
      __builtin_amdgcn_global_load_lds((const AS1 void*)sa, (AS3 void*)(As + c*1024 + l*16), 16, 0, 0);
      __builtin_amdgcn_global_load_lds((const AS1 void*)sb, (AS3 void*)(Bs + c*1024 + l*16), 16, 0, 0);
    }
    __syncthreads();
    #pragma unroll
    for(int ks=0; ks<2; ks++){
      short8 af[4], bf[4];
      #pragma unroll
      for(int f=0; f<4; f++){
        int rA = wave_m + f*16 + (l & 15);
        int ca = (ks*64 + (l>>4)*16) ^ ((rA & 7) << 4);
        af[f] = *(const short8*)(As + rA*128 + ca);
        int rB = wave_n + f*16 + (l & 15);
        int cb = (ks*64 + (l>>4)*16) ^ ((rB & 7) << 4);
        bf[f] = *(const short8*)(Bs + rB*128 + cb);
      }
      #pragma unroll
      for(int mf=0; mf<4; mf++){
        #pragma unroll
        for(int nf=0; nf<4; nf++){
          acc[mf][nf] = __builtin_amdgcn_mfma_f32_16x16x32_bf16(af[mf], bf[nf], acc[mf][nf], 0, 0, 0);
        }
      }
    }
    __syncthreads();
  }
  __hip_bfloat16* outp = linrP + (size_t)i*2097152;
  #pragma unroll
  for(int mf=0; mf<4; mf++){
    #pragma unroll
    for(int nf=0; nf<4; nf++){
      #pragma unroll
      for(int r=0; r<4; r++){
        size_t m = wave_m + mf*16 + ((l>>4)<<2) + r;
        size_t n = wave_n + nf*16 + (l & 15);
        outp[(b0+m)*512 + n0+n] = __float2bfloat16(acc[mf][nf][r]);
      }
    }
  }
}

// ---------------- k_left: leftB[j][b][m] = sum_n xP[j][b][n]*wlP[j][m][n]  (MFMA) ----------------
__global__ __launch_bounds__(256) void k_left(const __hip_bfloat16* __restrict__ xP,
                                              const __hip_bfloat16* __restrict__ wlP,
                                              float* __restrict__ leftB){
  const int tid = threadIdx.x;
  const int l = tid & 63, w = tid >> 6;
  const int j = blockIdx.y;
  const int row = blockIdx.x*64 + w*16 + (l & 15);
  floatx4 acc[2] = {};
  const __hip_bfloat16* Ap = xP + (size_t)j*2097152;
  const __hip_bfloat16* Wp = wlP + (size_t)j*16384;
  for(int nc=0; nc<16; nc++){
    int nb = nc*32 + (l>>4)*8;
    short8 a  = *(const short8*)(Ap + (size_t)row*512 + nb);
    short8 b0 = *(const short8*)(Wp + (l&15)*512 + nb);
    short8 b1 = *(const short8*)(Wp + ((l&15)+16)*512 + nb);
    acc[0] = __builtin_amdgcn_mfma_f32_16x16x32_bf16(a, b0, acc[0], 0, 0, 0);
    acc[1] = __builtin_amdgcn_mfma_f32_16x16x32_bf16(a, b1, acc[1], 0, 0, 0);
  }
  #pragma unroll
  for(int mf=0; mf<2; mf++){
    #pragma unroll
    for(int r=0; r<4; r++){
      int b = blockIdx.x*64 + w*16 + (l>>4)*4 + r;
      leftB[(size_t)j*131072 + b*32 + mf*16 + (l&15)] = acc[mf][r];
    }
  }
}

// ---------------- knorm: normalize linrP planes -> xrI interleaved bf16 [e][k] ----------------
__global__ __launch_bounds__(256) void knorm(const __hip_bfloat16* __restrict__ linrP,
                                             const float* __restrict__ norm_a,
                                             __hip_bfloat16* __restrict__ xrI){
  const size_t base = ((size_t)blockIdx.x*256 + threadIdx.x) * 8;
  const short* lp = (const short*)linrP;
  short8 v[8];
  #pragma unroll
  for(int i=0;i<8;i++) v[i] = *(const short8*)(lp + (size_t)i*2097152 + base);
  short8 o[8];
  #pragma unroll
  for(int s=0;s<8;s++){
    float u[8];
    #pragma unroll
    for(int i=0;i<8;i++) u[i] = bf2f(v[i][s]);
    int n = (int)((base + s) & 511);
    float4 na = *(const float4*)(norm_a + n*4);
    norm8v(u, na);
    #pragma unroll
    for(int i=0;i<8;i++) o[s][i] = f2bf(u[i]);
  }
  short* op = (short*)xrI;
  #pragma unroll
  for(int s=0;s<8;s++) *(short8*)(op + (base+s)*8) = o[s];
}

// ---------------- k2_mfma: fcgp1 product via per-j register-built A fragments (R6 config) ----------------
// Bpack layout: [n>>2][j][q][m][i] — 16KB contiguous per 4-n group.
__global__ __launch_bounds__(256) void k2_mfma(const float* __restrict__ x,
                                               const __hip_bfloat16* __restrict__ xrI,
                                               const __hip_bfloat16* __restrict__ Bpack,
                                               float* __restrict__ h1part){
  const int tid = threadIdx.x;
  const int l = tid & 63, w = tid >> 6;
  const int row = blockIdx.x*64 + w*16 + (l & 15);
  const int nsb = blockIdx.y * 64;
  const int boff = (l>>4)*256 + (l&15)*8;
  floatx4 acc[8][2] = {};

  for(int nc = 0; nc < 16; nc++){
    const int n = nsb + nc*4 + (l>>4);
    const size_t e = (size_t)row*512 + n;
    float4 xa = *(const float4*)(x + e*8);
    float4 xb = *(const float4*)(x + e*8 + 4);
    float xv[8] = {xa.x,xa.y,xa.z,xa.w,xb.x,xb.y,xb.z,xb.w};
    short8 xri = *(const short8*)((const short*)xrI + e*8);
    float xr[8];
    #pragma unroll
    for(int i=0;i<8;i++) xr[i] = bf2f(xri[i]);
    const __hip_bfloat16* bp_nc = Bpack + (size_t)(blockIdx.y*16 + nc)*8192 + boff;
    #pragma unroll
    for(int j=0;j<8;j++){
      short8 af;
      #pragma unroll
      for(int i=0;i<8;i++) af[i] = f2bf(xv[i] * xr[c_kof(j,i)]);
      short8 b0 = *(const short8*)(bp_nc + j*1024);
      short8 b1 = *(const short8*)(bp_nc + j*1024 + 128);
      acc[j][0] = __builtin_amdgcn_mfma_f32_16x16x32_bf16(af, b0, acc[j][0], 0, 0, 0);
      acc[j][1] = __builtin_amdgcn_mfma_f32_16x16x32_bf16(af, b1, acc[j][1], 0, 0, 0);
    }
  }
  const int sp = blockIdx.y;
  #pragma unroll
  for(int j=0;j<8;j++){
    #pragma unroll
    for(int mf=0; mf<2; mf++){
      #pragma unroll
      for(int r=0; r<4; r++){
        int b = blockIdx.x*64 + w*16 + (l>>4)*4 + r;
        h1part[((size_t)(sp*8+j))*131072 + b*32 + mf*16 + (l&15)] = acc[j][mf][r];
      }
    }
  }
}

// ---------------- K2b: reduce + left + bias + silu -> h1s f32 + h1P bf16 planes ----------------
__global__ __launch_bounds__(256) void k2b_silu(const float* __restrict__ h1part,
                                                const float* __restrict__ leftB,
                                                const float* __restrict__ bl,
                                                const float* __restrict__ sa,
                                                const float* __restrict__ sb,
                                                float* __restrict__ h1s,
                                                __hip_bfloat16* __restrict__ h1P){
  int idx = blockIdx.x*256 + threadIdx.x;  // b*32+m
  int m = idx & 31;
  float v[8];
  #pragma unroll
  for(int j=0;j<8;j++){
    float s = leftB[(size_t)j*131072 + idx];
    #pragma unroll
    for(int sp=0; sp<8; sp++) s += h1part[((size_t)(sp*8+j))*131072 + idx];
    v[j] = s;
  }
  v[0] += bl[m];
  #pragma unroll
  for(int i=0;i<8;i++) v[i] *= INV_SQRT2F;
  float q1 = v[1]*v[1]+v[2]*v[2]+v[3]*v[3];
  float q2 = v[4]*v[4]+v[5]*v[5]+v[6]*v[6];
  float q3 = v[7]*v[7];
  float4 sa4 = *(const float4*)&sa[m*4];
  float4 sb4 = *(const float4*)&sb[m*4];
  float g0 = sigf(sa4.x*v[0] + sb4.x);
  float g1 = sigf(sa4.y*q1   + sb4.y);
  float g2 = sigf(sa4.z*q2   + sb4.z);
  float g3 = sigf(sa4.w*q3   + sb4.w);
  float o[8] = {g0*v[0], g1*v[1], g1*v[2], g1*v[3], g2*v[4], g2*v[5], g2*v[6], g3*v[7]};
  *(float4*)&h1s[(size_t)idx*8]     = make_float4(o[0],o[1],o[2],o[3]);
  *(float4*)&h1s[(size_t)idx*8 + 4] = make_float4(o[4],o[5],o[6],o[7]);
  #pragma unroll
  for(int j=0;j<8;j++) h1P[(size_t)j*131072 + idx] = __float2bfloat16(o[j]);
}

// ---------------- k3a: linr2/left2 [j][b][n] = sum_m h1P[j][b][m] * w2{r,l}P[j][n][m] ----------------
__global__ __launch_bounds__(256) void k3a(const __hip_bfloat16* __restrict__ h1P,
                                           const __hip_bfloat16* __restrict__ w2rP,
                                           const __hip_bfloat16* __restrict__ w2lP,
                                           float* __restrict__ linr2,
                                           float* __restrict__ left2){
  const int tid = threadIdx.x;
  const int l = tid & 63, w = tid >> 6;
  const int j = blockIdx.y;
  const int row = blockIdx.x*64 + w*16 + (l & 15);
  const int ko = (l>>4)*8;
  short8 a   = *(const short8*)(h1P + (size_t)j*131072 + (size_t)row*32 + ko);
  short8 br0 = *(const short8*)(w2rP + j*1024 + (l&15)*32 + ko);
  short8 br1 = *(const short8*)(w2rP + j*1024 + ((l&15)+16)*32 + ko);
  short8 bl0 = *(const short8*)(w2lP + j*1024 + (l&15)*32 + ko);
  short8 bl1 = *(const short8*)(w2lP + j*1024 + ((l&15)+16)*32 + ko);
  floatx4 aR0 = {}, aR1 = {}, aL0 = {}, aL1 = {};
  aR0 = __builtin_amdgcn_mfma_f32_16x16x32_bf16(a, br0, aR0, 0, 0, 0);
  aR1 = __builtin_amdgcn_mfma_f32_16x16x32_bf16(a, br1, aR1, 0, 0, 0);
  aL0 = __builtin_amdgcn_mfma_f32_16x16x32_bf16(a, bl0, aL0, 0, 0, 0);
  aL1 = __builtin_amdgcn_mfma_f32_16x16x32_bf16(a, bl1, aL1, 0, 0, 0);
  #pragma unroll
  for(int r=0; r<4; r++){
    int b = blockIdx.x*64 + w*16 + (l>>4)*4 + r;
    linr2[(size_t)j*131072 + b*32 + (l&15)]      = aR0[r];
    linr2[(size_t)j*131072 + b*32 + 16 + (l&15)] = aR1[r];
    left2[(size_t)j*131072 + b*32 + (l&15)]      = aL0[r];
    left2[(size_t)j*131072 + b*32 + 16 + (l&15)] = aL1[r];
  }
}

// ---------------- k3b: norm(linr2) -> x2; sgp + left2 + bias + silu -> h2f, h2P ----------------
// gw2 (8KB) staged in LDS with +1 padding: bank = (n + wix) mod 32 -> conflict-free.
__global__ __launch_bounds__(256) void k3b(const float* __restrict__ linr2,
                                           const float* __restrict__ left2,
                                           const float* __restrict__ h1s,
                                           const float* __restrict__ na2,
                                           const float* __restrict__ gw2,
                                           const float* __restrict__ b2l,
                                           const float* __restrict__ sa,
                                           const float* __restrict__ sb,
                                           float* __restrict__ h2f,
                                           __hip_bfloat16* __restrict__ h2P){
  __shared__ float g2s[32][65];
  {
    const float4* src = (const float4*)gw2;   // 32*64 floats = 512 float4
    #pragma unroll
    for(int r=0; r<2; r++){
      int t = threadIdx.x + r*256;
      float4 v = src[t];
      int n = t >> 4;
      int c = (t & 15) * 4;
      g2s[n][c]=v.x; g2s[n][c+1]=v.y; g2s[n][c+2]=v.z; g2s[n][c+3]=v.w;
    }
  }
  __syncthreads();
  int idx = blockIdx.x*256 + threadIdx.x;  // b*32+n
  int n = idx & 31;
  float x2[8];
  #pragma unroll
  for(int j=0;j<8;j++) x2[j] = linr2[(size_t)j*131072 + idx];
  norm8v(x2, *(const float4*)&na2[n*4]);
  float4 h0 = *(const float4*)&h1s[(size_t)idx*8];
  float4 h1 = *(const float4*)&h1s[(size_t)idx*8 + 4];
  float h[8] = {h0.x,h0.y,h0.z,h0.w,h1.x,h1.y,h1.z,h1.w};
  float v[8];
  #pragma unroll
  for(int j=0;j<8;j++){
    float pr = 0.f;
    #pragma unroll
    for(int i=0;i<8;i++)
      pr = fmaf(c_cs(j,i) * h[i] * x2[c_kof(j,i)], g2s[n][c_widx(j,i)], pr);
    v[j] = (pr + left2[(size_t)j*131072 + idx] + ((j==0) ? b2l[n] : 0.f)) * INV_SQRT2F;
  }
  float q1 = v[1]*v[1]+v[2]*v[2]+v[3]*v[3];
  float q2 = v[4]*v[4]+v[5]*v[5]+v[6]*v[6];
  float q3 = v[7]*v[7];
  float4 sa4 = *(const float4*)&sa[n*4];
  float4 sb4 = *(const float4*)&sb[n*4];
  float g0 = sigf(sa4.x*v[0] + sb4.x);
  float g1 = sigf(sa4.y*q1   + sb4.y);
  float gg2 = sigf(sa4.z*q2  + sb4.z);
  float g3 = sigf(sa4.w*q3   + sb4.w);
  float o[8] = {g0*v[0], g1*v[1], g1*v[2], g1*v[3], gg2*v[4], gg2*v[5], gg2*v[6], g3*v[7]};
  *(float4*)&h2f[(size_t)idx*8]     = make_float4(o[0],o[1],o[2],o[3]);
  *(float4*)&h2f[(size_t)idx*8 + 4] = make_float4(o[4],o[5],o[6],o[7]);
  #pragma unroll
  for(int j=0;j<8;j++) h2P[(size_t)j*131072 + idx] = __float2bfloat16(o[j]);
}

// ---------------- k3c: linr3[j][b][n] = sum_m h2P[j][b][m] * w3rP[j][n][m] ----------------
__global__ __launch_bounds__(256) void k3c(const __hip_bfloat16* __restrict__ h2P,
                                           const __hip_bfloat16* __restrict__ w3rP,
                                           float* __restrict__ linr3){
  const int tid = threadIdx.x;
  const int l = tid & 63, w = tid >> 6;
  const int j = blockIdx.y;
  const int row = blockIdx.x*64 + w*16 + (l & 15);
  const int ko = (l>>4)*8;
  short8 a   = *(const short8*)(h2P + (size_t)j*131072 + (size_t)row*32 + ko);
  short8 b0  = *(const short8*)(w3rP + j*1024 + (l&15)*32 + ko);
  short8 b1  = *(const short8*)(w3rP + j*1024 + ((l&15)+16)*32 + ko);
  floatx4 a0 = {}, a1 = {};
  a0 = __builtin_amdgcn_mfma_f32_16x16x32_bf16(a, b0, a0, 0, 0, 0);
  a1 = __builtin_amdgcn_mfma_f32_16x16x32_bf16(a, b1, a1, 0, 0, 0);
  #pragma unroll
  for(int r=0; r<4; r++){
    int b = blockIdx.x*64 + w*16 + (l>>4)*4 + r;
    linr3[(size_t)j*131072 + b*32 + (l&15)]      = a0[r];
    linr3[(size_t)j*131072 + b*32 + 16 + (l&15)] = a1[r];
  }
}

// ---------------- k3d: norm(linr3) -> x3; pairP[j][b][n*8+i] = bf16(h2[i]*x3[kof(j,i)]) ----------------
__global__ __launch_bounds__(256) void k3d(const float* __restrict__ linr3,
                                           const float* __restrict__ h2f,
                                           const float* __restrict__ na3,
                                           __hip_bfloat16* __restrict__ pairP){
  int idx = blockIdx.x*256 + threadIdx.x;  // b*32+n
  int n = idx & 31;
  float x3[8];
  #pragma unroll
  for(int j=0;j<8;j++) x3[j] = linr3[(size_t)j*131072 + idx];
  norm8v(x3, *(const float4*)&na3[n*4]);
  float4 h0 = *(const float4*)&h2f[(size_t)idx*8];
  float4 h1 = *(const float4*)&h2f[(size_t)idx*8 + 4];
  float h[8] = {h0.x,h0.y,h0.z,h0.w,h1.x,h1.y,h1.z,h1.w};
  #pragma unroll
  for(int j=0;j<8;j++){
    short8 o;
    #pragma unroll
    for(int i=0;i<8;i++) o[i] = f2bf(h[i] * x3[c_kof(j,i)]);
    *(short8*)(pairP + (size_t)j*1048576 + (size_t)idx*8) = o;
  }
}

// ---------------- k3e: out[b][mo][j] = (sum_k pair/h2 x Bp3 + bias) * c ----------------
__global__ __launch_bounds__(256) void k3e(const __hip_bfloat16* __restrict__ pairP,
                                           const __hip_bfloat16* __restrict__ h2P,
                                           const __hip_bfloat16* __restrict__ Bp3,
                                           const float* __restrict__ b3l,
                                           float* __restrict__ out){
  const int tid = threadIdx.x;
  const int l = tid & 63, w = tid >> 6;
  const int j = blockIdx.y;
  const int row = blockIdx.x*64 + w*16 + (l & 15);
  const int mo = l & 15;
  const int ko = (l>>4)*8;
  floatx4 acc = {};
  const __hip_bfloat16* Ap = pairP + (size_t)j*1048576 + (size_t)row*256;
  const __hip_bfloat16* Bp = Bp3 + (size_t)j*4608 + mo*288;
  #pragma unroll
  for(int kc=0; kc<8; kc++){
    short8 a = *(const short8*)(Ap + kc*32 + ko);
    short8 b = *(const short8*)(Bp + kc*32 + ko);
    acc = __builtin_amdgcn_mfma_f32_16x16x32_bf16(a, b, acc, 0, 0, 0);
  }
  {
    short8 a = *(const short8*)(h2P + (size_t)j*131072 + (size_t)row*32 + ko);
    short8 b = *(const short8*)(Bp + 256 + ko);
    acc = __builtin_amdgcn_mfma_f32_16x16x32_bf16(a, b, acc, 0, 0, 0);
  }
  if(mo < 9){
    #pragma unroll
    for(int r=0; r<4; r++){
      int b = blockIdx.x*64 + w*16 + (l>>4)*4 + r;
      out[((size_t)b*9 + mo)*8 + j] = (acc[r] + ((j==0) ? b3l[mo] : 0.f)) * INV_SQRT2F;
    }
  }
}

// ---------------- launch ----------------
extern "C" void kernel_launch(void* const* d_in, const int* in_sizes, int n_in,
                              void* d_out, int out_size, void* d_ws, size_t ws_size,
                              hipStream_t stream){
  const float* x        = (const float*)d_in[0];
  const float* w_right1 = (const float*)d_in[1];
  const float* norm_a1  = (const float*)d_in[2];
  const float* w_left1  = (const float*)d_in[3];
  const float* b_left1  = (const float*)d_in[4];
  const float* gp_w1    = (const float*)d_in[5];
  const float* silu_a   = (const float*)d_in[6];
  const float* silu_b   = (const float*)d_in[7];
  const float* w_right2 = (const float*)d_in[8];
  const float* norm_a2  = (const float*)d_in[9];
  const float* w_left2  = (const float*)d_in[10];
  const float* b_left2  = (const float*)d_in[11];
  const float* gp_w2    = (const float*)d_in[12];
  const float* w_right3 = (const float*)d_in[13];
  const float* norm_a3  = (const float*)d_in[14];
  const float* w_left3  = (const float*)d_in[15];
  const float* b_left3  = (const float*)d_in[16];
  const float* gp_w3    = (const float*)d_in[17];
  float* out = (float*)d_out;

  char* wsb = (char*)d_ws;
  __hip_bfloat16* xP    = (__hip_bfloat16*)wsb;
  __hip_bfloat16* xrI   = (__hip_bfloat16*)wsb;
  __hip_bfloat16* pairP = (__hip_bfloat16*)wsb;
  float*          linr2 = (float*)(wsb + 16777216);
  float*          left2 = (float*)(wsb + 20971520);
  float*          h2f   = (float*)(wsb + 25165824);
  __hip_bfloat16* h2P   = (__hip_bfloat16*)(wsb + 29360128);
  __hip_bfloat16* wP    = (__hip_bfloat16*)(wsb + 33554432);
  __hip_bfloat16* h1P   = (__hip_bfloat16*)(wsb + 33554432);
  float*          h1s   = (float*)(wsb + 35651584);
  __hip_bfloat16* linrP = (__hip_bfloat16*)(wsb + 41943040);
  float*          h1part= (float*)(wsb + 41943040);
  float*          linr3 = (float*)(wsb + 41943040);
  __hip_bfloat16* Bpack = (__hip_bfloat16*)(wsb + 75497472);
  __hip_bfloat16* wlP   = (__hip_bfloat16*)(wsb + 77594624);
  float*          leftB = (float*)(wsb + 77856768);
  __hip_bfloat16* w2rP  = (__hip_bfloat16*)(wsb + 82051072);
  __hip_bfloat16* w2lP  = (__hip_bfloat16*)(wsb + 82051072 + 16384);
  __hip_bfloat16* w3rP  = (__hip_bfloat16*)(wsb + 82051072 + 32768);
  __hip_bfloat16* Bp3   = (__hip_bfloat16*)(wsb + 82051072 + 49152);

  pack_x<<<8192, 256, 0, stream>>>(x, xP);
  pack_misc<<<2288, 256, 0, stream>>>(w_right1, gp_w1, w_left1,
                                      w_right2, w_left2, w_right3, gp_w3, w_left3,
                                      wP, Bpack, wlP, w2rP, w2lP, w3rP, Bp3);
  k1_mfma<<<dim3(32, 4, 8), 256, 0, stream>>>(xP, wP, linrP);
  k_left<<<dim3(64, 8), 256, 0, stream>>>(xP, wlP, leftB);
  knorm<<<1024, 256, 0, stream>>>(linrP, norm_a1, xrI);
  k2_mfma<<<dim3(64, 8), 256, 0, stream>>>(x, xrI, Bpack, h1part);
  k2b_silu<<<512, 256, 0, stream>>>(h1part, leftB, b_left1, silu_a, silu_b, h1s, h1P);
  k3a<<<dim3(64, 8), 256, 0, stream>>>(h1P, w2rP, w2lP, linr2, left2);
  k3b<<<512, 256, 0, stream>>>(linr2, left2, h1s, norm_a2, gp_w2, b_left2,
                               silu_a, silu_b, h2f, h2P);
  k3c<<<dim3(64, 8), 256, 0, stream>>>(h2P, w3rP, linr3);
  k3d<<<512, 256, 0, stream>>>(linr3, h2f, norm_a3, pairP);
  k3e<<<dim3(64, 8), 256, 0, stream>>>(pairP, h2P, Bp3, b_left3, out);
}

// Round 12
// 146.142 us; speedup vs baseline: 1.1793x; 1.0332x over previous
//
#include <hip/hip_runtime.h>
#include <hip/hip_bf16.h>
#include <math.h>

#define INV_SQRT2F 0.70710678118654752440f
#define AS1 __attribute__((address_space(1)))
#define AS3 __attribute__((address_space(3)))

typedef __attribute__((ext_vector_type(8))) short short8;
typedef __attribute__((ext_vector_type(4))) float floatx4;

// ---------------- compile-time algebra tables ----------------
struct Tables {
  int   kof[8][8];
  float cs[8][8];
  int   widx[8][8];
};
constexpr int t_bm(int i){ constexpr int t[8] = {0,1,2,4,3,5,6,7}; return t[i]; }
constexpr int t_idx(int b){ constexpr int t[8] = {0,1,2,4,3,5,6,7}; return t[b]; }
constexpr int t_gr(int i){ constexpr int t[8] = {0,1,1,1,2,2,2,3}; return t[i]; }
constexpr int t_pc(int x){ int c=0; while(x){ c += x&1; x >>= 1; } return c; }
constexpr float t_sign(int a, int b){
  float s = 1.f; int aa = a >> 1;
  while(aa){ if(t_pc(aa & b) & 1) s = -s; aa >>= 1; }
  return s;
}
constexpr int   c_kof(int j,int i){ return t_idx(t_bm(i)^t_bm(j)); }
constexpr float c_cs(int j,int i){ return t_sign(t_bm(i), t_bm(c_kof(j,i))); }
constexpr int   c_widx(int j,int i){ return t_gr(i)*16 + t_gr(j)*4 + t_gr(c_kof(j,i)); }
constexpr Tables mkTables(){
  Tables T{};
  for(int j=0;j<8;j++) for(int i=0;i<8;i++){
    T.kof[j][i]  = c_kof(j,i);
    T.cs[j][i]   = c_cs(j,i);
    T.widx[j][i] = c_widx(j,i);
  }
  return T;
}
__device__ const Tables d_TB = mkTables();

__device__ __forceinline__ float rcpf(float v){ return __builtin_amdgcn_rcpf(v); }
__device__ __forceinline__ float sigf(float z){ return rcpf(1.f + __expf(-z)); }
__device__ __forceinline__ int gradeOfIdx(int i){ return (i==0)?0:((i<4)?1:((i<7)?2:3)); }
__device__ __forceinline__ short f2bf(float v){
  __hip_bfloat16 h = __float2bfloat16(v);
  short s; __builtin_memcpy(&s, &h, 2); return s;
}
__device__ __forceinline__ float bf2f(short s){
  unsigned int w = ((unsigned int)(unsigned short)s) << 16;
  float f; __builtin_memcpy(&f, &w, 4); return f;
}
__device__ __forceinline__ void norm8v(float* v, float4 na){
  float s0 = sigf(na.x)*(fabsf(v[0])-1.f)+1.f+1e-6f;
  float s1 = sigf(na.y)*(sqrtf(v[1]*v[1]+v[2]*v[2]+v[3]*v[3])-1.f)+1.f+1e-6f;
  float s2 = sigf(na.z)*(sqrtf(v[4]*v[4]+v[5]*v[5]+v[6]*v[6])-1.f)+1.f+1e-6f;
  float s3 = sigf(na.w)*(fabsf(v[7])-1.f)+1.f+1e-6f;
  float r0 = rcpf(s0), r1 = rcpf(s1), r2 = rcpf(s2), r3 = rcpf(s3);
  v[0]*=r0; v[1]*=r1; v[2]*=r1; v[3]*=r1; v[4]*=r2; v[5]*=r2; v[6]*=r2; v[7]*=r3;
}

// ---------------- pack_x: x fp32 [b][m][8] -> 8 bf16 planes [i][b*512+m] ----------------
__global__ __launch_bounds__(256) void pack_x(const float* __restrict__ x,
                                              __hip_bfloat16* __restrict__ xP){
  size_t e = (size_t)blockIdx.x*256 + threadIdx.x;
  float4 u0 = *(const float4*)(x + e*8);
  float4 u1 = *(const float4*)(x + e*8 + 4);
  float u[8] = {u0.x,u0.y,u0.z,u0.w,u1.x,u1.y,u1.z,u1.w};
  #pragma unroll
  for(int i=0;i<8;i++) xP[(size_t)i*2097152 + e] = __float2bfloat16(u[i]);
}

// ---------------- pack_misc: fused small weight packs ----------------
__global__ __launch_bounds__(256) void pack_misc(const float* __restrict__ w,
                                                 const float* __restrict__ gpw,
                                                 const float* __restrict__ wl,
                                                 const float* __restrict__ w2r,
                                                 const float* __restrict__ w2l,
                                                 const float* __restrict__ w3r,
                                                 const float* __restrict__ gw3,
                                                 const float* __restrict__ w3l,
                                                 __hip_bfloat16* __restrict__ wP,
                                                 __hip_bfloat16* __restrict__ Bpack,
                                                 __hip_bfloat16* __restrict__ wlP,
                                                 __hip_bfloat16* __restrict__ w2rP,
                                                 __hip_bfloat16* __restrict__ w2lP,
                                                 __hip_bfloat16* __restrict__ w3rP,
                                                 __hip_bfloat16* __restrict__ Bp3){
  const int bx = blockIdx.x;
  if(bx < 1024){
    size_t e = (size_t)bx*256 + threadIdx.x;
    float4 u = *(const float4*)(w + e*4);
    float v[4] = {u.x,u.y,u.z,u.w};
    #pragma unroll
    for(int g=0; g<4; g++) wP[(size_t)g*262144 + e] = __float2bfloat16(v[g]);
  } else if(bx < 1536){
    int t = (bx-1024)*256 + threadIdx.x;          // j*16384 + n*32 + m
    int j = t >> 14; int n = (t >> 5) & 511; int m = t & 31;
    const float* src = gpw + ((size_t)m*512 + n)*64;
    short8 o;
    #pragma unroll
    for(int jj=0; jj<8; jj++){
      if(jj == j){
        #pragma unroll
        for(int i=0;i<8;i++) o[i] = f2bf(c_cs(jj,i) * src[c_widx(jj,i)]);
      }
    }
    int q = n & 3;
    *(short8*)(Bpack + (size_t)(n>>2)*8192 + j*1024 + q*256 + m*8) = o;
  } else if(bx < 2048){
    int t2 = (bx-1536)*256 + threadIdx.x;         // j*16384 + m*512 + n
    int j = t2 >> 14; int m = (t2 >> 9) & 31; int n = t2 & 511;
    int g = gradeOfIdx(j);
    wlP[t2] = __float2bfloat16(wl[((size_t)m*512 + n)*4 + g]);
  } else if(bx < 2144){
    int t = (bx-2048)*256 + threadIdx.x;
    int which = t >> 13; int r = t & 8191;
    int j = r >> 10; int n = (r >> 5) & 31; int m = r & 31;
    int g = gradeOfIdx(j);
    const float* src = (which==0) ? w2r : (which==1) ? w2l : w3r;
    __hip_bfloat16* dst = (which==0) ? w2rP : (which==1) ? w2lP : w3rP;
    dst[r] = __float2bfloat16(src[((size_t)n*32 + m)*4 + g]);
  } else {
    int t2 = (bx-2144)*256 + threadIdx.x;         // j*4608 + mo*288 + k
    if(t2 >= 36864) return;
    int j = t2 / 4608; int rem = t2 - j*4608;
    int mo = rem / 288; int k = rem - mo*288;
    float v = 0.f;
    if(mo < 9){
      if(k < 256){
        int n = k >> 3, i = k & 7;
        v = d_TB.cs[j][i] * gw3[((size_t)mo*32 + n)*64 + d_TB.widx[j][i]];
      } else {
        int n = k - 256;
        v = w3l[((size_t)mo*32 + n)*4 + gradeOfIdx(j)];
      }
    }
    Bp3[t2] = __float2bfloat16(v);
  }
}

// ---------------- K1 MFMA: linrP[i][b][n] = sum_m xP[i][b][m] * wP[g(i)][n][m] ----------------
// BM=128, BN=128, BK=64; grid (32,4,8)
__global__ __launch_bounds__(256) void k1_mfma(const __hip_bfloat16* __restrict__ xP,
                                               const __hip_bfloat16* __restrict__ wP,
                                               __hip_bfloat16* __restrict__ linrP){
  __shared__ __align__(16) char lds[32768];
  char* As = lds;
  char* Bs = lds + 16384;
  const int tid = threadIdx.x;
  const int l   = tid & 63;
  const int w   = tid >> 6;
  const int i   = blockIdx.z;
  const int g   = gradeOfIdx(i);
  const size_t b0 = (size_t)blockIdx.x * 128;
  const size_t n0 = (size_t)blockIdx.y * 128;
  const __hip_bfloat16* Ag = xP + (size_t)i*2097152;
  const __hip_bfloat16* Bg = wP + (size_t)g*262144;

  const int wave_m = (w & 1) * 64;
  const int wave_n = (w >> 1) * 64;
  const int srow = l >> 3;
  const int scol = ((l & 7) ^ srow) * 8;

  floatx4 acc[4][4] = {};

  for(int kt = 0; kt < 512; kt += 64){
    #pragma unroll
    for(int it=0; it<4; it++){
      int c   = it*4 + w;
      int row = c*8 + srow;
      const __hip_bfloat16* sa = Ag + (b0 + row)*512 + kt + scol;
      const __hip_bfloat16* sb = Bg + (n0 + row)*512 + kt + scol;
      __builtin_amdgcn_global_load_lds((const AS1 void*)sa, (AS3 void*)(As + c*1024 + l*16), 16, 0, 0);
      __builtin_amdgcn_global_load_lds((const AS1 void*)sb, (AS3 void*)(Bs + c*1024 + l*16), 16, 0, 0);
    }
    __syncthreads();
    #pragma unroll
    for(int ks=0; ks<2; ks++){
      short8 af[4], bf[4];
      #pragma unroll
      for(int f=0; f<4; f++){
        int rA = wave_m + f*16 + (l & 15);
        int ca = (ks*64 + (l>>4)*16) ^ ((rA & 7) << 4);
        af[f] = *(const short8*)(As + rA*128 + ca);
        int rB = wave_n + f*16 + (l & 15);
        int cb = (ks*64 + (l>>4)*16) ^ ((rB & 7) << 4);
        bf[f] = *(const short8*)(Bs + rB*128 + cb);
      }
      #pragma unroll
      for(int mf=0; mf<4; mf++){
        #pragma unroll
        for(int nf=0; nf<4; nf++){
          acc[mf][nf] = __builtin_amdgcn_mfma_f32_16x16x32_bf16(af[mf], bf[nf], acc[mf][nf], 0, 0, 0);
        }
      }
    }
    __syncthreads();
  }
  __hip_bfloat16* outp = linrP + (size_t)i*2097152;
  #pragma unroll
  for(int mf=0; mf<4; mf++){
    #pragma unroll
    for(int nf=0; nf<4; nf++){
      #pragma unroll
      for(int r=0; r<4; r++){
        size_t m = wave_m + mf*16 + ((l>>4)<<2) + r;
        size_t n = wave_n + nf*16 + (l & 15);
        outp[(b0+m)*512 + n0+n] = __float2bfloat16(acc[mf][nf][r]);
      }
    }
  }
}

// ---------------- k_left: leftB[j][b][m] = sum_n xP[j][b][n]*wlP[j][m][n]  (MFMA) ----------------
__global__ __launch_bounds__(256) void k_left(const __hip_bfloat16* __restrict__ xP,
                                              const __hip_bfloat16* __restrict__ wlP,
                                              float* __restrict__ leftB){
  const int tid = threadIdx.x;
  const int l = tid & 63, w = tid >> 6;
  const int j = blockIdx.y;
  const int row = blockIdx.x*64 + w*16 + (l & 15);
  floatx4 acc[2] = {};
  const __hip_bfloat16* Ap = xP + (size_t)j*2097152;
  const __hip_bfloat16* Wp = wlP + (size_t)j*16384;
  for(int nc=0; nc<16; nc++){
    int nb = nc*32 + (l>>4)*8;
    short8 a  = *(const short8*)(Ap + (size_t)row*512 + nb);
    short8 b0 = *(const short8*)(Wp + (l&15)*512 + nb);
    short8 b1 = *(const short8*)(Wp + ((l&15)+16)*512 + nb);
    acc[0] = __builtin_amdgcn_mfma_f32_16x16x32_bf16(a, b0, acc[0], 0, 0, 0);
    acc[1] = __builtin_amdgcn_mfma_f32_16x16x32_bf16(a, b1, acc[1], 0, 0, 0);
  }
  #pragma unroll
  for(int mf=0; mf<2; mf++){
    #pragma unroll
    for(int r=0; r<4; r++){
      int b = blockIdx.x*64 + w*16 + (l>>4)*4 + r;
      leftB[(size_t)j*131072 + b*32 + mf*16 + (l&15)] = acc[mf][r];
    }
  }
}

// ---------------- knorm: normalize linrP planes -> xrI interleaved bf16 [e][k] ----------------
__global__ __launch_bounds__(256) void knorm(const __hip_bfloat16* __restrict__ linrP,
                                             const float* __restrict__ norm_a,
                                             __hip_bfloat16* __restrict__ xrI){
  const size_t base = ((size_t)blockIdx.x*256 + threadIdx.x) * 8;
  const short* lp = (const short*)linrP;
  short8 v[8];
  #pragma unroll
  for(int i=0;i<8;i++) v[i] = *(const short8*)(lp + (size_t)i*2097152 + base);
  short8 o[8];
  #pragma unroll
  for(int s=0;s<8;s++){
    float u[8];
    #pragma unroll
    for(int i=0;i<8;i++) u[i] = bf2f(v[i][s]);
    int n = (int)((base + s) & 511);
    float4 na = *(const float4*)(norm_a + n*4);
    norm8v(u, na);
    #pragma unroll
    for(int i=0;i<8;i++) o[s][i] = f2bf(u[i]);
  }
  short* op = (short*)xrI;
  #pragma unroll
  for(int s=0;s<8;s++) *(short8*)(op + (base+s)*8) = o[s];
}

// ---------------- k2_mfma: fcgp1 product; Bpack chunk staged in LDS (double-buffered) ----------------
// Bpack layout: [n>>2][j][q][m][i] — 16KB contiguous per 4-n group. All 4 waves
// in a block read the SAME chunk -> cooperative global_load_lds (linear dest),
// one barrier per nc: stage(nc+1 -> other buf) || compute(nc), barrier drains both.
__global__ __launch_bounds__(256) void k2_mfma(const float* __restrict__ x,
                                               const __hip_bfloat16* __restrict__ xrI,
                                               const __hip_bfloat16* __restrict__ Bpack,
                                               float* __restrict__ h1part){
  __shared__ __align__(16) char bsh[2][16384];
  const int tid = threadIdx.x;
  const int l = tid & 63, w = tid >> 6;
  const int row = blockIdx.x*64 + w*16 + (l & 15);
  const int nsb = blockIdx.y * 64;
  const int boffB = (l>>4)*512 + (l&15)*16;   // byte offset within j's 2KB span
  floatx4 acc[8][2] = {};

  const char* chunk0 = (const char*)(Bpack + (size_t)(blockIdx.y*16)*8192);
  // prologue: stage chunk 0 into buf 0
  #pragma unroll
  for(int it=0; it<4; it++){
    int off = (it*256 + tid)*16;
    __builtin_amdgcn_global_load_lds((const AS1 void*)(chunk0 + off), (AS3 void*)(&bsh[0][0] + off), 16, 0, 0);
  }
  __syncthreads();

  for(int nc = 0; nc < 16; nc++){
    if(nc < 15){
      const char* src = (const char*)(Bpack + (size_t)(blockIdx.y*16 + nc + 1)*8192);
      char* dst = &bsh[(nc+1)&1][0];
      #pragma unroll
      for(int it=0; it<4; it++){
        int off = (it*256 + tid)*16;
        __builtin_amdgcn_global_load_lds((const AS1 void*)(src + off), (AS3 void*)(dst + off), 16, 0, 0);
      }
    }
    const int n = nsb + nc*4 + (l>>4);
    const size_t e = (size_t)row*512 + n;
    float4 xa = *(const float4*)(x + e*8);
    float4 xb = *(const float4*)(x + e*8 + 4);
    float xv[8] = {xa.x,xa.y,xa.z,xa.w,xb.x,xb.y,xb.z,xb.w};
    short8 xri = *(const short8*)((const short*)xrI + e*8);
    float xr[8];
    #pragma unroll
    for(int i=0;i<8;i++) xr[i] = bf2f(xri[i]);
    const char* bcur = &bsh[nc&1][0];
    #pragma unroll
    for(int j=0;j<8;j++){
      short8 af;
      #pragma unroll
      for(int i=0;i<8;i++) af[i] = f2bf(xv[i] * xr[c_kof(j,i)]);
      short8 b0 = *(const short8*)(bcur + j*2048 + boffB);
      short8 b1 = *(const short8*)(bcur + j*2048 + boffB + 256);
      acc[j][0] = __builtin_amdgcn_mfma_f32_16x16x32_bf16(af, b0, acc[j][0], 0, 0, 0);
      acc[j][1] = __builtin_amdgcn_mfma_f32_16x16x32_bf16(af, b1, acc[j][1], 0, 0, 0);
    }
    __syncthreads();   // drains stage(nc+1) + all waves done reading buf nc&1
  }
  const int sp = blockIdx.y;
  #pragma unroll
  for(int j=0;j<8;j++){
    #pragma unroll
    for(int mf=0; mf<2; mf++){
      #pragma unroll
      for(int r=0; r<4; r++){
        int b = blockIdx.x*64 + w*16 + (l>>4)*4 + r;
        h1part[((size_t)(sp*8+j))*131072 + b*32 + mf*16 + (l&15)] = acc[j][mf][r];
      }
    }
  }
}

// ---------------- K2b: reduce + left + bias + silu -> h1s f32 + h1P bf16 planes ----------------
__global__ __launch_bounds__(256) void k2b_silu(const float* __restrict__ h1part,
                                                const float* __restrict__ leftB,
                                                const float* __restrict__ bl,
                                                const float* __restrict__ sa,
                                                const float* __restrict__ sb,
                                                float* __restrict__ h1s,
                                                __hip_bfloat16* __restrict__ h1P){
  int idx = blockIdx.x*256 + threadIdx.x;  // b*32+m
  int m = idx & 31;
  float v[8];
  #pragma unroll
  for(int j=0;j<8;j++){
    float s = leftB[(size_t)j*131072 + idx];
    #pragma unroll
    for(int sp=0; sp<8; sp++) s += h1part[((size_t)(sp*8+j))*131072 + idx];
    v[j] = s;
  }
  v[0] += bl[m];
  #pragma unroll
  for(int i=0;i<8;i++) v[i] *= INV_SQRT2F;
  float q1 = v[1]*v[1]+v[2]*v[2]+v[3]*v[3];
  float q2 = v[4]*v[4]+v[5]*v[5]+v[6]*v[6];
  float q3 = v[7]*v[7];
  float4 sa4 = *(const float4*)&sa[m*4];
  float4 sb4 = *(const float4*)&sb[m*4];
  float g0 = sigf(sa4.x*v[0] + sb4.x);
  float g1 = sigf(sa4.y*q1   + sb4.y);
  float g2 = sigf(sa4.z*q2   + sb4.z);
  float g3 = sigf(sa4.w*q3   + sb4.w);
  float o[8] = {g0*v[0], g1*v[1], g1*v[2], g1*v[3], g2*v[4], g2*v[5], g2*v[6], g3*v[7]};
  *(float4*)&h1s[(size_t)idx*8]     = make_float4(o[0],o[1],o[2],o[3]);
  *(float4*)&h1s[(size_t)idx*8 + 4] = make_float4(o[4],o[5],o[6],o[7]);
  #pragma unroll
  for(int j=0;j<8;j++) h1P[(size_t)j*131072 + idx] = __float2bfloat16(o[j]);
}

// ---------------- k3a: linr2/left2 [j][b][n] = sum_m h1P[j][b][m] * w2{r,l}P[j][n][m] ----------------
__global__ __launch_bounds__(256) void k3a(const __hip_bfloat16* __restrict__ h1P,
                                           const __hip_bfloat16* __restrict__ w2rP,
                                           const __hip_bfloat16* __restrict__ w2lP,
                                           float* __restrict__ linr2,
                                           float* __restrict__ left2){
  const int tid = threadIdx.x;
  const int l = tid & 63, w = tid >> 6;
  const int j = blockIdx.y;
  const int row = blockIdx.x*64 + w*16 + (l & 15);
  const int ko = (l>>4)*8;
  short8 a   = *(const short8*)(h1P + (size_t)j*131072 + (size_t)row*32 + ko);
  short8 br0 = *(const short8*)(w2rP + j*1024 + (l&15)*32 + ko);
  short8 br1 = *(const short8*)(w2rP + j*1024 + ((l&15)+16)*32 + ko);
  short8 bl0 = *(const short8*)(w2lP + j*1024 + (l&15)*32 + ko);
  short8 bl1 = *(const short8*)(w2lP + j*1024 + ((l&15)+16)*32 + ko);
  floatx4 aR0 = {}, aR1 = {}, aL0 = {}, aL1 = {};
  aR0 = __builtin_amdgcn_mfma_f32_16x16x32_bf16(a, br0, aR0, 0, 0, 0);
  aR1 = __builtin_amdgcn_mfma_f32_16x16x32_bf16(a, br1, aR1, 0, 0, 0);
  aL0 = __builtin_amdgcn_mfma_f32_16x16x32_bf16(a, bl0, aL0, 0, 0, 0);
  aL1 = __builtin_amdgcn_mfma_f32_16x16x32_bf16(a, bl1, aL1, 0, 0, 0);
  #pragma unroll
  for(int r=0; r<4; r++){
    int b = blockIdx.x*64 + w*16 + (l>>4)*4 + r;
    linr2[(size_t)j*131072 + b*32 + (l&15)]      = aR0[r];
    linr2[(size_t)j*131072 + b*32 + 16 + (l&15)] = aR1[r];
    left2[(size_t)j*131072 + b*32 + (l&15)]      = aL0[r];
    left2[(size_t)j*131072 + b*32 + 16 + (l&15)] = aL1[r];
  }
}

// ---------------- k3b: norm(linr2) -> x2; sgp + left2 + bias + silu -> h2f, h2P ----------------
// gw2 (8KB) staged in LDS with +1 padding: bank = (n + wix) mod 32 -> conflict-free.
__global__ __launch_bounds__(256) void k3b(const float* __restrict__ linr2,
                                           const float* __restrict__ left2,
                                           const float* __restrict__ h1s,
                                           const float* __restrict__ na2,
                                           const float* __restrict__ gw2,
                                           const float* __restrict__ b2l,
                                           const float* __restrict__ sa,
                                           const float* __restrict__ sb,
                                           float* __restrict__ h2f,
                                           __hip_bfloat16* __restrict__ h2P){
  __shared__ float g2s[32][65];
  {
    const float4* src = (const float4*)gw2;   // 32*64 floats = 512 float4
    #pragma unroll
    for(int r=0; r<2; r++){
      int t = threadIdx.x + r*256;
      float4 v = src[t];
      int n = t >> 4;
      int c = (t & 15) * 4;
      g2s[n][c]=v.x; g2s[n][c+1]=v.y; g2s[n][c+2]=v.z; g2s[n][c+3]=v.w;
    }
  }
  __syncthreads();
  int idx = blockIdx.x*256 + threadIdx.x;  // b*32+n
  int n = idx & 31;
  float x2[8];
  #pragma unroll
  for(int j=0;j<8;j++) x2[j] = linr2[(size_t)j*131072 + idx];
  norm8v(x2, *(const float4*)&na2[n*4]);
  float4 h0 = *(const float4*)&h1s[(size_t)idx*8];
  float4 h1 = *(const float4*)&h1s[(size_t)idx*8 + 4];
  float h[8] = {h0.x,h0.y,h0.z,h0.w,h1.x,h1.y,h1.z,h1.w};
  float v[8];
  #pragma unroll
  for(int j=0;j<8;j++){
    float pr = 0.f;
    #pragma unroll
    for(int i=0;i<8;i++)
      pr = fmaf(c_cs(j,i) * h[i] * x2[c_kof(j,i)], g2s[n][c_widx(j,i)], pr);
    v[j] = (pr + left2[(size_t)j*131072 + idx] + ((j==0) ? b2l[n] : 0.f)) * INV_SQRT2F;
  }
  float q1 = v[1]*v[1]+v[2]*v[2]+v[3]*v[3];
  float q2 = v[4]*v[4]+v[5]*v[5]+v[6]*v[6];
  float q3 = v[7]*v[7];
  float4 sa4 = *(const float4*)&sa[n*4];
  float4 sb4 = *(const float4*)&sb[n*4];
  float g0 = sigf(sa4.x*v[0] + sb4.x);
  float g1 = sigf(sa4.y*q1   + sb4.y);
  float gg2 = sigf(sa4.z*q2  + sb4.z);
  float g3 = sigf(sa4.w*q3   + sb4.w);
  float o[8] = {g0*v[0], g1*v[1], g1*v[2], g1*v[3], gg2*v[4], gg2*v[5], gg2*v[6], g3*v[7]};
  *(float4*)&h2f[(size_t)idx*8]     = make_float4(o[0],o[1],o[2],o[3]);
  *(float4*)&h2f[(size_t)idx*8 + 4] = make_float4(o[4],o[5],o[6],o[7]);
  #pragma unroll
  for(int j=0;j<8;j++) h2P[(size_t)j*131072 + idx] = __float2bfloat16(o[j]);
}

// ---------------- k3c: linr3[j][b][n] = sum_m h2P[j][b][m] * w3rP[j][n][m] ----------------
__global__ __launch_bounds__(256) void k3c(const __hip_bfloat16* __restrict__ h2P,
                                           const __hip_bfloat16* __restrict__ w3rP,
                                           float* __restrict__ linr3){
  const int tid = threadIdx.x;
  const int l = tid & 63, w = tid >> 6;
  const int j = blockIdx.y;
  const int row = blockIdx.x*64 + w*16 + (l & 15);
  const int ko = (l>>4)*8;
  short8 a   = *(const short8*)(h2P + (size_t)j*131072 + (size_t)row*32 + ko);
  short8 b0  = *(const short8*)(w3rP + j*1024 + (l&15)*32 + ko);
  short8 b1  = *(const short8*)(w3rP + j*1024 + ((l&15)+16)*32 + ko);
  floatx4 a0 = {}, a1 = {};
  a0 = __builtin_amdgcn_mfma_f32_16x16x32_bf16(a, b0, a0, 0, 0, 0);
  a1 = __builtin_amdgcn_mfma_f32_16x16x32_bf16(a, b1, a1, 0, 0, 0);
  #pragma unroll
  for(int r=0; r<4; r++){
    int b = blockIdx.x*64 + w*16 + (l>>4)*4 + r;
    linr3[(size_t)j*131072 + b*32 + (l&15)]      = a0[r];
    linr3[(size_t)j*131072 + b*32 + 16 + (l&15)] = a1[r];
  }
}

// ---------------- k3d: norm(linr3) -> x3; pairP[j][b][n*8+i] = bf16(h2[i]*x3[kof(j,i)]) ----------------
__global__ __launch_bounds__(256) void k3d(const float* __restrict__ linr3,
                                           const float* __restrict__ h2f,
                                           const float* __restrict__ na3,
                                           __hip_bfloat16* __restrict__ pairP){
  int idx = blockIdx.x*256 + threadIdx.x;  // b*32+n
  int n = idx & 31;
  float x3[8];
  #pragma unroll
  for(int j=0;j<8;j++) x3[j] = linr3[(size_t)j*131072 + idx];
  norm8v(x3, *(const float4*)&na3[n*4]);
  float4 h0 = *(const float4*)&h2f[(size_t)idx*8];
  float4 h1 = *(const float4*)&h2f[(size_t)idx*8 + 4];
  float h[8] = {h0.x,h0.y,h0.z,h0.w,h1.x,h1.y,h1.z,h1.w};
  #pragma unroll
  for(int j=0;j<8;j++){
    short8 o;
    #pragma unroll
    for(int i=0;i<8;i++) o[i] = f2bf(h[i] * x3[c_kof(j,i)]);
    *(short8*)(pairP + (size_t)j*1048576 + (size_t)idx*8) = o;
  }
}

// ---------------- k3e: out[b][mo][j] = (sum_k pair/h2 x Bp3 + bias) * c ----------------
__global__ __launch_bounds__(256) void k3e(const __hip_bfloat16* __restrict__ pairP,
                                           const __hip_bfloat16* __restrict__ h2P,
                                           const __hip_bfloat16* __restrict__ Bp3,
                                           const float* __restrict__ b3l,
                                           float* __restrict__ out){
  const int tid = threadIdx.x;
  const int l = tid & 63, w = tid >> 6;
  const int j = blockIdx.y;
  const int row = blockIdx.x*64 + w*16 + (l & 15);
  const int mo = l & 15;
  const int ko = (l>>4)*8;
  floatx4 acc = {};
  const __hip_bfloat16* Ap = pairP + (size_t)j*1048576 + (size_t)row*256;
  const __hip_bfloat16* Bp = Bp3 + (size_t)j*4608 + mo*288;
  #pragma unroll
  for(int kc=0; kc<8; kc++){
    short8 a = *(const short8*)(Ap + kc*32 + ko);
    short8 b = *(const short8*)(Bp + kc*32 + ko);
    acc = __builtin_amdgcn_mfma_f32_16x16x32_bf16(a, b, acc, 0, 0, 0);
  }
  {
    short8 a = *(const short8*)(h2P + (size_t)j*131072 + (size_t)row*32 + ko);
    short8 b = *(const short8*)(Bp + 256 + ko);
    acc = __builtin_amdgcn_mfma_f32_16x16x32_bf16(a, b, acc, 0, 0, 0);
  }
  if(mo < 9){
    #pragma unroll
    for(int r=0; r<4; r++){
      int b = blockIdx.x*64 + w*16 + (l>>4)*4 + r;
      out[((size_t)b*9 + mo)*8 + j] = (acc[r] + ((j==0) ? b3l[mo] : 0.f)) * INV_SQRT2F;
    }
  }
}

// ---------------- launch ----------------
extern "C" void kernel_launch(void* const* d_in, const int* in_sizes, int n_in,
                              void* d_out, int out_size, void* d_ws, size_t ws_size,
                              hipStream_t stream){
  const float* x        = (const float*)d_in[0];
  const float* w_right1 = (const float*)d_in[1];
  const float* norm_a1  = (const float*)d_in[2];
  const float* w_left1  = (const float*)d_in[3];
  const float* b_left1  = (const float*)d_in[4];
  const float* gp_w1    = (const float*)d_in[5];
  const float* silu_a   = (const float*)d_in[6];
  const float* silu_b   = (const float*)d_in[7];
  const float* w_right2 = (const float*)d_in[8];
  const float* norm_a2  = (const float*)d_in[9];
  const float* w_left2  = (const float*)d_in[10];
  const float* b_left2  = (const float*)d_in[11];
  const float* gp_w2    = (const float*)d_in[12];
  const float* w_right3 = (const float*)d_in[13];
  const float* norm_a3  = (const float*)d_in[14];
  const float* w_left3  = (const float*)d_in[15];
  const float* b_left3  = (const float*)d_in[16];
  const float* gp_w3    = (const float*)d_in[17];
  float* out = (float*)d_out;

  char* wsb = (char*)d_ws;
  __hip_bfloat16* xP    = (__hip_bfloat16*)wsb;
  __hip_bfloat16* xrI   = (__hip_bfloat16*)wsb;
  __hip_bfloat16* pairP = (__hip_bfloat16*)wsb;
  float*          linr2 = (float*)(wsb + 16777216);
  float*          left2 = (float*)(wsb + 20971520);
  float*          h2f   = (float*)(wsb + 25165824);
  __hip_bfloat16* h2P   = (__hip_bfloat16*)(wsb + 29360128);
  __hip_bfloat16* wP    = (__hip_bfloat16*)(wsb + 33554432);
  __hip_bfloat16* h1P   = (__hip_bfloat16*)(wsb + 33554432);
  float*          h1s   = (float*)(wsb + 35651584);
  __hip_bfloat16* linrP = (__hip_bfloat16*)(wsb + 41943040);
  float*          h1part= (float*)(wsb + 41943040);
  float*          linr3 = (float*)(wsb + 41943040);
  __hip_bfloat16* Bpack = (__hip_bfloat16*)(wsb + 75497472);
  __hip_bfloat16* wlP   = (__hip_bfloat16*)(wsb + 77594624);
  float*          leftB = (float*)(wsb + 77856768);
  __hip_bfloat16* w2rP  = (__hip_bfloat16*)(wsb + 82051072);
  __hip_bfloat16* w2lP  = (__hip_bfloat16*)(wsb + 82051072 + 16384);
  __hip_bfloat16* w3rP  = (__hip_bfloat16*)(wsb + 82051072 + 32768);
  __hip_bfloat16* Bp3   = (__hip_bfloat16*)(wsb + 82051072 + 49152);

  pack_x<<<8192, 256, 0, stream>>>(x, xP);
  pack_misc<<<2288, 256, 0, stream>>>(w_right1, gp_w1, w_left1,
                                      w_right2, w_left2, w_right3, gp_w3, w_left3,
                                      wP, Bpack, wlP, w2rP, w2lP, w3rP, Bp3);
  k1_mfma<<<dim3(32, 4, 8), 256, 0, stream>>>(xP, wP, linrP);
  k_left<<<dim3(64, 8), 256, 0, stream>>>(xP, wlP, leftB);
  knorm<<<1024, 256, 0, stream>>>(linrP, norm_a1, xrI);
  k2_mfma<<<dim3(64, 8), 256, 0, stream>>>(x, xrI, Bpack, h1part);
  k2b_silu<<<512, 256, 0, stream>>>(h1part, leftB, b_left1, silu_a, silu_b, h1s, h1P);
  k3a<<<dim3(64, 8), 256, 0, stream>>>(h1P, w2rP, w2lP, linr2, left2);
  k3b<<<512, 256, 0, stream>>>(linr2, left2, h1s, norm_a2, gp_w2, b_left2,
                               silu_a, silu_b, h2f, h2P);
  k3c<<<dim3(64, 8), 256, 0, stream>>>(h2P, w3rP, linr3);
  k3d<<<512, 256, 0, stream>>>(linr3, h2f, norm_a3, pairP);
  k3e<<<dim3(64, 8), 256, 0, stream>>>(pairP, h2P, Bp3, b_left3, out);
}

// Round 13
// 144.971 us; speedup vs baseline: 1.1888x; 1.0081x over previous
//
#include <hip/hip_runtime.h>
#include <hip/hip_bf16.h>
#include <math.h>

#define INV_SQRT2F 0.70710678118654752440f
#define AS1 __attribute__((address_space(1)))
#define AS3 __attribute__((address_space(3)))

typedef __attribute__((ext_vector_type(8))) short short8;
typedef __attribute__((ext_vector_type(4))) float floatx4;

// ---------------- compile-time algebra tables ----------------
struct Tables {
  int   kof[8][8];
  float cs[8][8];
  int   widx[8][8];
};
constexpr int t_bm(int i){ constexpr int t[8] = {0,1,2,4,3,5,6,7}; return t[i]; }
constexpr int t_idx(int b){ constexpr int t[8] = {0,1,2,4,3,5,6,7}; return t[b]; }
constexpr int t_gr(int i){ constexpr int t[8] = {0,1,1,1,2,2,2,3}; return t[i]; }
constexpr int t_pc(int x){ int c=0; while(x){ c += x&1; x >>= 1; } return c; }
constexpr float t_sign(int a, int b){
  float s = 1.f; int aa = a >> 1;
  while(aa){ if(t_pc(aa & b) & 1) s = -s; aa >>= 1; }
  return s;
}
constexpr int   c_kof(int j,int i){ return t_idx(t_bm(i)^t_bm(j)); }
constexpr float c_cs(int j,int i){ return t_sign(t_bm(i), t_bm(c_kof(j,i))); }
constexpr int   c_widx(int j,int i){ return t_gr(i)*16 + t_gr(j)*4 + t_gr(c_kof(j,i)); }
constexpr Tables mkTables(){
  Tables T{};
  for(int j=0;j<8;j++) for(int i=0;i<8;i++){
    T.kof[j][i]  = c_kof(j,i);
    T.cs[j][i]   = c_cs(j,i);
    T.widx[j][i] = c_widx(j,i);
  }
  return T;
}
__device__ const Tables d_TB = mkTables();

__device__ __forceinline__ float rcpf(float v){ return __builtin_amdgcn_rcpf(v); }
__device__ __forceinline__ float sigf(float z){ return rcpf(1.f + __expf(-z)); }
__device__ __forceinline__ int gradeOfIdx(int i){ return (i==0)?0:((i<4)?1:((i<7)?2:3)); }
__device__ __forceinline__ short f2bf(float v){
  __hip_bfloat16 h = __float2bfloat16(v);
  short s; __builtin_memcpy(&s, &h, 2); return s;
}
__device__ __forceinline__ float bf2f(short s){
  unsigned int w = ((unsigned int)(unsigned short)s) << 16;
  float f; __builtin_memcpy(&f, &w, 4); return f;
}
__device__ __forceinline__ void norm8v(float* v, float4 na){
  float s0 = sigf(na.x)*(fabsf(v[0])-1.f)+1.f+1e-6f;
  float s1 = sigf(na.y)*(sqrtf(v[1]*v[1]+v[2]*v[2]+v[3]*v[3])-1.f)+1.f+1e-6f;
  float s2 = sigf(na.z)*(sqrtf(v[4]*v[4]+v[5]*v[5]+v[6]*v[6])-1.f)+1.f+1e-6f;
  float s3 = sigf(na.w)*(fabsf(v[7])-1.f)+1.f+1e-6f;
  float r0 = rcpf(s0), r1 = rcpf(s1), r2 = rcpf(s2), r3 = rcpf(s3);
  v[0]*=r0; v[1]*=r1; v[2]*=r1; v[3]*=r1; v[4]*=r2; v[5]*=r2; v[6]*=r2; v[7]*=r3;
}

// ---------------- pack_all: pack_x (bx<8192) + weight packs ----------------
__global__ __launch_bounds__(256) void pack_all(const float* __restrict__ x,
                                                const float* __restrict__ w,
                                                const float* __restrict__ gpw,
                                                const float* __restrict__ wl,
                                                const float* __restrict__ w2r,
                                                const float* __restrict__ w2l,
                                                const float* __restrict__ w3r,
                                                const float* __restrict__ gw3,
                                                const float* __restrict__ w3l,
                                                __hip_bfloat16* __restrict__ xP,
                                                __hip_bfloat16* __restrict__ wP,
                                                __hip_bfloat16* __restrict__ Bpack,
                                                __hip_bfloat16* __restrict__ wlP,
                                                __hip_bfloat16* __restrict__ w2rP,
                                                __hip_bfloat16* __restrict__ w2lP,
                                                __hip_bfloat16* __restrict__ w3rP,
                                                __hip_bfloat16* __restrict__ Bp3){
  const int bx = blockIdx.x;
  if(bx < 8192){
    size_t e = (size_t)bx*256 + threadIdx.x;
    float4 u0 = *(const float4*)(x + e*8);
    float4 u1 = *(const float4*)(x + e*8 + 4);
    float u[8] = {u0.x,u0.y,u0.z,u0.w,u1.x,u1.y,u1.z,u1.w};
    #pragma unroll
    for(int i=0;i<8;i++) xP[(size_t)i*2097152 + e] = __float2bfloat16(u[i]);
  } else if(bx < 9216){
    size_t e = (size_t)(bx-8192)*256 + threadIdx.x;
    float4 u = *(const float4*)(w + e*4);
    float v[4] = {u.x,u.y,u.z,u.w};
    #pragma unroll
    for(int g=0; g<4; g++) wP[(size_t)g*262144 + e] = __float2bfloat16(v[g]);
  } else if(bx < 9728){
    int t = (bx-9216)*256 + threadIdx.x;          // j*16384 + n*32 + m
    int j = t >> 14; int n = (t >> 5) & 511; int m = t & 31;
    const float* src = gpw + ((size_t)m*512 + n)*64;
    short8 o;
    #pragma unroll
    for(int jj=0; jj<8; jj++){
      if(jj == j){
        #pragma unroll
        for(int i=0;i<8;i++) o[i] = f2bf(c_cs(jj,i) * src[c_widx(jj,i)]);
      }
    }
    int q = n & 3;
    *(short8*)(Bpack + (size_t)(n>>2)*8192 + j*1024 + q*256 + m*8) = o;
  } else if(bx < 10240){
    int t2 = (bx-9728)*256 + threadIdx.x;         // j*16384 + m*512 + n
    int j = t2 >> 14; int m = (t2 >> 9) & 31; int n = t2 & 511;
    int g = gradeOfIdx(j);
    wlP[t2] = __float2bfloat16(wl[((size_t)m*512 + n)*4 + g]);
  } else if(bx < 10336){
    int t = (bx-10240)*256 + threadIdx.x;
    int which = t >> 13; int r = t & 8191;
    int j = r >> 10; int n = (r >> 5) & 31; int m = r & 31;
    int g = gradeOfIdx(j);
    const float* src = (which==0) ? w2r : (which==1) ? w2l : w3r;
    __hip_bfloat16* dst = (which==0) ? w2rP : (which==1) ? w2lP : w3rP;
    dst[r] = __float2bfloat16(src[((size_t)n*32 + m)*4 + g]);
  } else {
    int t2 = (bx-10336)*256 + threadIdx.x;        // j*4608 + mo*288 + k
    if(t2 >= 36864) return;
    int j = t2 / 4608; int rem = t2 - j*4608;
    int mo = rem / 288; int k = rem - mo*288;
    float v = 0.f;
    if(mo < 9){
      if(k < 256){
        int n = k >> 3, i = k & 7;
        v = d_TB.cs[j][i] * gw3[((size_t)mo*32 + n)*64 + d_TB.widx[j][i]];
      } else {
        int n = k - 256;
        v = w3l[((size_t)mo*32 + n)*4 + gradeOfIdx(j)];
      }
    }
    Bp3[t2] = __float2bfloat16(v);
  }
}

// ---------------- K1 MFMA: linrP[i][b][n] = sum_m xP[i][b][m] * wP[g(i)][n][m] ----------------
// BM=128, BN=128, BK=64; grid (32,4,8)
__global__ __launch_bounds__(256) void k1_mfma(const __hip_bfloat16* __restrict__ xP,
                                               const __hip_bfloat16* __restrict__ wP,
                                               __hip_bfloat16* __restrict__ linrP){
  __shared__ __align__(16) char lds[32768];
  char* As = lds;
  char* Bs = lds + 16384;
  const int tid = threadIdx.x;
  const int l   = tid & 63;
  const int w   = tid >> 6;
  const int i   = blockIdx.z;
  const int g   = gradeOfIdx(i);
  const size_t b0 = (size_t)blockIdx.x * 128;
  const size_t n0 = (size_t)blockIdx.y * 128;
  const __hip_bfloat16* Ag = xP + (size_t)i*2097152;
  const __hip_bfloat16* Bg = wP + (size_t)g*262144;

  const int wave_m = (w & 1) * 64;
  const int wave_n = (w >> 1) * 64;
  const int srow = l >> 3;
  const int scol = ((l & 7) ^ srow) * 8;

  floatx4 acc[4][4] = {};

  for(int kt = 0; kt < 512; kt += 64){
    #pragma unroll
    for(int it=0; it<4; it++){
      int c   = it*4 + w;
      int row = c*8 + srow;
      const __hip_bfloat16* sa = Ag + (b0 + row)*512 + kt + scol;
      const __hip_bfloat16* sb = Bg + (n0 + row)*512 + kt + scol;
      __builtin_amdgcn_global_load_lds((const AS1 void*)sa, (AS3 void*)(As + c*1024 + l*16), 16, 0, 0);
      __builtin_amdgcn_global_load_lds((const AS1 void*)sb, (AS3 void*)(Bs + c*1024 + l*16), 16, 0, 0);
    }
    __syncthreads();
    #pragma unroll
    for(int ks=0; ks<2; ks++){
      short8 af[4], bf[4];
      #pragma unroll
      for(int f=0; f<4; f++){
        int rA = wave_m + f*16 + (l & 15);
        int ca = (ks*64 + (l>>4)*16) ^ ((rA & 7) << 4);
        af[f] = *(const short8*)(As + rA*128 + ca);
        int rB = wave_n + f*16 + (l & 15);
        int cb = (ks*64 + (l>>4)*16) ^ ((rB & 7) << 4);
        bf[f] = *(const short8*)(Bs + rB*128 + cb);
      }
      #pragma unroll
      for(int mf=0; mf<4; mf++){
        #pragma unroll
        for(int nf=0; nf<4; nf++){
          acc[mf][nf] = __builtin_amdgcn_mfma_f32_16x16x32_bf16(af[mf], bf[nf], acc[mf][nf], 0, 0, 0);
        }
      }
    }
    __syncthreads();
  }
  __hip_bfloat16* outp = linrP + (size_t)i*2097152;
  #pragma unroll
  for(int mf=0; mf<4; mf++){
    #pragma unroll
    for(int nf=0; nf<4; nf++){
      #pragma unroll
      for(int r=0; r<4; r++){
        size_t m = wave_m + mf*16 + ((l>>4)<<2) + r;
        size_t n = wave_n + nf*16 + (l & 15);
        outp[(b0+m)*512 + n0+n] = __float2bfloat16(acc[mf][nf][r]);
      }
    }
  }
}

// ---------------- k_left: leftB[j][b][m] = sum_n xP[j][b][n]*wlP[j][m][n]  (MFMA) ----------------
__global__ __launch_bounds__(256) void k_left(const __hip_bfloat16* __restrict__ xP,
                                              const __hip_bfloat16* __restrict__ wlP,
                                              float* __restrict__ leftB){
  const int tid = threadIdx.x;
  const int l = tid & 63, w = tid >> 6;
  const int j = blockIdx.y;
  const int row = blockIdx.x*64 + w*16 + (l & 15);
  floatx4 acc[2] = {};
  const __hip_bfloat16* Ap = xP + (size_t)j*2097152;
  const __hip_bfloat16* Wp = wlP + (size_t)j*16384;
  for(int nc=0; nc<16; nc++){
    int nb = nc*32 + (l>>4)*8;
    short8 a  = *(const short8*)(Ap + (size_t)row*512 + nb);
    short8 b0 = *(const short8*)(Wp + (l&15)*512 + nb);
    short8 b1 = *(const short8*)(Wp + ((l&15)+16)*512 + nb);
    acc[0] = __builtin_amdgcn_mfma_f32_16x16x32_bf16(a, b0, acc[0], 0, 0, 0);
    acc[1] = __builtin_amdgcn_mfma_f32_16x16x32_bf16(a, b1, acc[1], 0, 0, 0);
  }
  #pragma unroll
  for(int mf=0; mf<2; mf++){
    #pragma unroll
    for(int r=0; r<4; r++){
      int b = blockIdx.x*64 + w*16 + (l>>4)*4 + r;
      leftB[(size_t)j*131072 + b*32 + mf*16 + (l&15)] = acc[mf][r];
    }
  }
}

// ---------------- knorm: normalize linrP planes -> xrI interleaved bf16 [e][k] ----------------
__global__ __launch_bounds__(256) void knorm(const __hip_bfloat16* __restrict__ linrP,
                                             const float* __restrict__ norm_a,
                                             __hip_bfloat16* __restrict__ xrI){
  const size_t base = ((size_t)blockIdx.x*256 + threadIdx.x) * 8;
  const short* lp = (const short*)linrP;
  short8 v[8];
  #pragma unroll
  for(int i=0;i<8;i++) v[i] = *(const short8*)(lp + (size_t)i*2097152 + base);
  short8 o[8];
  #pragma unroll
  for(int s=0;s<8;s++){
    float u[8];
    #pragma unroll
    for(int i=0;i<8;i++) u[i] = bf2f(v[i][s]);
    int n = (int)((base + s) & 511);
    float4 na = *(const float4*)(norm_a + n*4);
    norm8v(u, na);
    #pragma unroll
    for(int i=0;i<8;i++) o[s][i] = f2bf(u[i]);
  }
  short* op = (short*)xrI;
  #pragma unroll
  for(int s=0;s<8;s++) *(short8*)(op + (base+s)*8) = o[s];
}

// ---------------- k2_mfma: fcgp1 product; 2 Bpack chunks per barrier (BK-doubled) ----------------
// Bpack layout: [n>>2][j][q][m][i] — 16KB contiguous per 4-n group; chunks contiguous.
// Double buffer of 32KB (2 chunks each); occupancy unchanged (grid-capped at 2 blocks/CU).
__global__ __launch_bounds__(256) void k2_mfma(const float* __restrict__ x,
                                               const __hip_bfloat16* __restrict__ xrI,
                                               const __hip_bfloat16* __restrict__ Bpack,
                                               float* __restrict__ h1part){
  __shared__ __align__(16) char bsh[65536];
  const int tid = threadIdx.x;
  const int l = tid & 63, w = tid >> 6;
  const int row = blockIdx.x*64 + w*16 + (l & 15);
  const int nsb = blockIdx.y * 64;
  const int boffB = (l>>4)*512 + (l&15)*16;   // byte offset within j's 2KB span
  floatx4 acc[8][2] = {};

  const char* base = (const char*)(Bpack + (size_t)(blockIdx.y*16)*8192);
  // prologue: stage pair 0 (chunks 0,1 = 32KB) into buf 0
  #pragma unroll
  for(int it=0; it<8; it++){
    int off = (it*256 + tid)*16;
    __builtin_amdgcn_global_load_lds((const AS1 void*)(base + off), (AS3 void*)(bsh + off), 16, 0, 0);
  }
  __syncthreads();

  for(int p = 0; p < 8; p++){
    if(p < 7){
      const char* src = base + (size_t)(p+1)*32768;
      char* dst = bsh + ((p+1)&1)*32768;
      #pragma unroll
      for(int it=0; it<8; it++){
        int off = (it*256 + tid)*16;
        __builtin_amdgcn_global_load_lds((const AS1 void*)(src + off), (AS3 void*)(dst + off), 16, 0, 0);
      }
    }
    const char* bufp = bsh + (p&1)*32768;
    #pragma unroll
    for(int sub=0; sub<2; sub++){
      const int nc = p*2 + sub;
      const int n = nsb + nc*4 + (l>>4);
      const size_t e = (size_t)row*512 + n;
      float4 xa = *(const float4*)(x + e*8);
      float4 xb = *(const float4*)(x + e*8 + 4);
      float xv[8] = {xa.x,xa.y,xa.z,xa.w,xb.x,xb.y,xb.z,xb.w};
      short8 xri = *(const short8*)((const short*)xrI + e*8);
      float xr[8];
      #pragma unroll
      for(int i=0;i<8;i++) xr[i] = bf2f(xri[i]);
      const char* bcur = bufp + sub*16384;
      #pragma unroll
      for(int j=0;j<8;j++){
        short8 af;
        #pragma unroll
        for(int i=0;i<8;i++) af[i] = f2bf(xv[i] * xr[c_kof(j,i)]);
        short8 b0 = *(const short8*)(bcur + j*2048 + boffB);
        short8 b1 = *(const short8*)(bcur + j*2048 + boffB + 256);
        acc[j][0] = __builtin_amdgcn_mfma_f32_16x16x32_bf16(af, b0, acc[j][0], 0, 0, 0);
        acc[j][1] = __builtin_amdgcn_mfma_f32_16x16x32_bf16(af, b1, acc[j][1], 0, 0, 0);
      }
    }
    __syncthreads();   // drains stage(p+1) + all waves done reading buf p&1
  }
  const int sp = blockIdx.y;
  #pragma unroll
  for(int j=0;j<8;j++){
    #pragma unroll
    for(int mf=0; mf<2; mf++){
      #pragma unroll
      for(int r=0; r<4; r++){
        int b = blockIdx.x*64 + w*16 + (l>>4)*4 + r;
        h1part[((size_t)(sp*8+j))*131072 + b*32 + mf*16 + (l&15)] = acc[j][mf][r];
      }
    }
  }
}

// ---------------- K2b: reduce + left + bias + silu -> h1s f32 + h1P bf16 planes ----------------
__global__ __launch_bounds__(256) void k2b_silu(const float* __restrict__ h1part,
                                                const float* __restrict__ leftB,
                                                const float* __restrict__ bl,
                                                const float* __restrict__ sa,
                                                const float* __restrict__ sb,
                                                float* __restrict__ h1s,
                                                __hip_bfloat16* __restrict__ h1P){
  int idx = blockIdx.x*256 + threadIdx.x;  // b*32+m
  int m = idx & 31;
  float v[8];
  #pragma unroll
  for(int j=0;j<8;j++){
    float s = leftB[(size_t)j*131072 + idx];
    #pragma unroll
    for(int sp=0; sp<8; sp++) s += h1part[((size_t)(sp*8+j))*131072 + idx];
    v[j] = s;
  }
  v[0] += bl[m];
  #pragma unroll
  for(int i=0;i<8;i++) v[i] *= INV_SQRT2F;
  float q1 = v[1]*v[1]+v[2]*v[2]+v[3]*v[3];
  float q2 = v[4]*v[4]+v[5]*v[5]+v[6]*v[6];
  float q3 = v[7]*v[7];
  float4 sa4 = *(const float4*)&sa[m*4];
  float4 sb4 = *(const float4*)&sb[m*4];
  float g0 = sigf(sa4.x*v[0] + sb4.x);
  float g1 = sigf(sa4.y*q1   + sb4.y);
  float g2 = sigf(sa4.z*q2   + sb4.z);
  float g3 = sigf(sa4.w*q3   + sb4.w);
  float o[8] = {g0*v[0], g1*v[1], g1*v[2], g1*v[3], g2*v[4], g2*v[5], g2*v[6], g3*v[7]};
  *(float4*)&h1s[(size_t)idx*8]     = make_float4(o[0],o[1],o[2],o[3]);
  *(float4*)&h1s[(size_t)idx*8 + 4] = make_float4(o[4],o[5],o[6],o[7]);
  #pragma unroll
  for(int j=0;j<8;j++) h1P[(size_t)j*131072 + idx] = __float2bfloat16(o[j]);
}

// ---------------- k3a: linr2/left2 [j][b][n] = sum_m h1P[j][b][m] * w2{r,l}P[j][n][m] ----------------
__global__ __launch_bounds__(256) void k3a(const __hip_bfloat16* __restrict__ h1P,
                                           const __hip_bfloat16* __restrict__ w2rP,
                                           const __hip_bfloat16* __restrict__ w2lP,
                                           float* __restrict__ linr2,
                                           float* __restrict__ left2){
  const int tid = threadIdx.x;
  const int l = tid & 63, w = tid >> 6;
  const int j = blockIdx.y;
  const int row = blockIdx.x*64 + w*16 + (l & 15);
  const int ko = (l>>4)*8;
  short8 a   = *(const short8*)(h1P + (size_t)j*131072 + (size_t)row*32 + ko);
  short8 br0 = *(const short8*)(w2rP + j*1024 + (l&15)*32 + ko);
  short8 br1 = *(const short8*)(w2rP + j*1024 + ((l&15)+16)*32 + ko);
  short8 bl0 = *(const short8*)(w2lP + j*1024 + (l&15)*32 + ko);
  short8 bl1 = *(const short8*)(w2lP + j*1024 + ((l&15)+16)*32 + ko);
  floatx4 aR0 = {}, aR1 = {}, aL0 = {}, aL1 = {};
  aR0 = __builtin_amdgcn_mfma_f32_16x16x32_bf16(a, br0, aR0, 0, 0, 0);
  aR1 = __builtin_amdgcn_mfma_f32_16x16x32_bf16(a, br1, aR1, 0, 0, 0);
  aL0 = __builtin_amdgcn_mfma_f32_16x16x32_bf16(a, bl0, aL0, 0, 0, 0);
  aL1 = __builtin_amdgcn_mfma_f32_16x16x32_bf16(a, bl1, aL1, 0, 0, 0);
  #pragma unroll
  for(int r=0; r<4; r++){
    int b = blockIdx.x*64 + w*16 + (l>>4)*4 + r;
    linr2[(size_t)j*131072 + b*32 + (l&15)]      = aR0[r];
    linr2[(size_t)j*131072 + b*32 + 16 + (l&15)] = aR1[r];
    left2[(size_t)j*131072 + b*32 + (l&15)]      = aL0[r];
    left2[(size_t)j*131072 + b*32 + 16 + (l&15)] = aL1[r];
  }
}

// ---------------- k3b: norm(linr2) -> x2; sgp + left2 + bias + silu -> h2f, h2P ----------------
// gw2 (8KB) staged in LDS with +1 padding: bank = (n + wix) mod 32 -> conflict-free.
__global__ __launch_bounds__(256) void k3b(const float* __restrict__ linr2,
                                           const float* __restrict__ left2,
                                           const float* __restrict__ h1s,
                                           const float* __restrict__ na2,
                                           const float* __restrict__ gw2,
                                           const float* __restrict__ b2l,
                                           const float* __restrict__ sa,
                                           const float* __restrict__ sb,
                                           float* __restrict__ h2f,
                                           __hip_bfloat16* __restrict__ h2P){
  __shared__ float g2s[32][65];
  {
    const float4* src = (const float4*)gw2;   // 32*64 floats = 512 float4
    #pragma unroll
    for(int r=0; r<2; r++){
      int t = threadIdx.x + r*256;
      float4 v = src[t];
      int n = t >> 4;
      int c = (t & 15) * 4;
      g2s[n][c]=v.x; g2s[n][c+1]=v.y; g2s[n][c+2]=v.z; g2s[n][c+3]=v.w;
    }
  }
  __syncthreads();
  int idx = blockIdx.x*256 + threadIdx.x;  // b*32+n
  int n = idx & 31;
  float x2[8];
  #pragma unroll
  for(int j=0;j<8;j++) x2[j] = linr2[(size_t)j*131072 + idx];
  norm8v(x2, *(const float4*)&na2[n*4]);
  float4 h0 = *(const float4*)&h1s[(size_t)idx*8];
  float4 h1 = *(const float4*)&h1s[(size_t)idx*8 + 4];
  float h[8] = {h0.x,h0.y,h0.z,h0.w,h1.x,h1.y,h1.z,h1.w};
  float v[8];
  #pragma unroll
  for(int j=0;j<8;j++){
    float pr = 0.f;
    #pragma unroll
    for(int i=0;i<8;i++)
      pr = fmaf(c_cs(j,i) * h[i] * x2[c_kof(j,i)], g2s[n][c_widx(j,i)], pr);
    v[j] = (pr + left2[(size_t)j*131072 + idx] + ((j==0) ? b2l[n] : 0.f)) * INV_SQRT2F;
  }
  float q1 = v[1]*v[1]+v[2]*v[2]+v[3]*v[3];
  float q2 = v[4]*v[4]+v[5]*v[5]+v[6]*v[6];
  float q3 = v[7]*v[7];
  float4 sa4 = *(const float4*)&sa[n*4];
  float4 sb4 = *(const float4*)&sb[n*4];
  float g0 = sigf(sa4.x*v[0] + sb4.x);
  float g1 = sigf(sa4.y*q1   + sb4.y);
  float gg2 = sigf(sa4.z*q2  + sb4.z);
  float g3 = sigf(sa4.w*q3   + sb4.w);
  float o[8] = {g0*v[0], g1*v[1], g1*v[2], g1*v[3], gg2*v[4], gg2*v[5], gg2*v[6], g3*v[7]};
  *(float4*)&h2f[(size_t)idx*8]     = make_float4(o[0],o[1],o[2],o[3]);
  *(float4*)&h2f[(size_t)idx*8 + 4] = make_float4(o[4],o[5],o[6],o[7]);
  #pragma unroll
  for(int j=0;j<8;j++) h2P[(size_t)j*131072 + idx] = __float2bfloat16(o[j]);
}

// ---------------- k3c: linr3[j][b][n] = sum_m h2P[j][b][m] * w3rP[j][n][m] ----------------
__global__ __launch_bounds__(256) void k3c(const __hip_bfloat16* __restrict__ h2P,
                                           const __hip_bfloat16* __restrict__ w3rP,
                                           float* __restrict__ linr3){
  const int tid = threadIdx.x;
  const int l = tid & 63, w = tid >> 6;
  const int j = blockIdx.y;
  const int row = blockIdx.x*64 + w*16 + (l & 15);
  const int ko = (l>>4)*8;
  short8 a   = *(const short8*)(h2P + (size_t)j*131072 + (size_t)row*32 + ko);
  short8 b0  = *(const short8*)(w3rP + j*1024 + (l&15)*32 + ko);
  short8 b1  = *(const short8*)(w3rP + j*1024 + ((l&15)+16)*32 + ko);
  floatx4 a0 = {}, a1 = {};
  a0 = __builtin_amdgcn_mfma_f32_16x16x32_bf16(a, b0, a0, 0, 0, 0);
  a1 = __builtin_amdgcn_mfma_f32_16x16x32_bf16(a, b1, a1, 0, 0, 0);
  #pragma unroll
  for(int r=0; r<4; r++){
    int b = blockIdx.x*64 + w*16 + (l>>4)*4 + r;
    linr3[(size_t)j*131072 + b*32 + (l&15)]      = a0[r];
    linr3[(size_t)j*131072 + b*32 + 16 + (l&15)] = a1[r];
  }
}

// ---------------- k3d: norm(linr3) -> x3; pairP[j][b][n*8+i] = bf16(h2[i]*x3[kof(j,i)]) ----------------
__global__ __launch_bounds__(256) void k3d(const float* __restrict__ linr3,
                                           const float* __restrict__ h2f,
                                           const float* __restrict__ na3,
                                           __hip_bfloat16* __restrict__ pairP){
  int idx = blockIdx.x*256 + threadIdx.x;  // b*32+n
  int n = idx & 31;
  float x3[8];
  #pragma unroll
  for(int j=0;j<8;j++) x3[j] = linr3[(size_t)j*131072 + idx];
  norm8v(x3, *(const float4*)&na3[n*4]);
  float4 h0 = *(const float4*)&h2f[(size_t)idx*8];
  float4 h1 = *(const float4*)&h2f[(size_t)idx*8 + 4];
  float h[8] = {h0.x,h0.y,h0.z,h0.w,h1.x,h1.y,h1.z,h1.w};
  #pragma unroll
  for(int j=0;j<8;j++){
    short8 o;
    #pragma unroll
    for(int i=0;i<8;i++) o[i] = f2bf(h[i] * x3[c_kof(j,i)]);
    *(short8*)(pairP + (size_t)j*1048576 + (size_t)idx*8) = o;
  }
}

// ---------------- k3e: out[b][mo][j] = (sum_k pair/h2 x Bp3 + bias) * c ----------------
__global__ __launch_bounds__(256) void k3e(const __hip_bfloat16* __restrict__ pairP,
                                           const __hip_bfloat16* __restrict__ h2P,
                                           const __hip_bfloat16* __restrict__ Bp3,
                                           const float* __restrict__ b3l,
                                           float* __restrict__ out){
  const int tid = threadIdx.x;
  const int l = tid & 63, w = tid >> 6;
  const int j = blockIdx.y;
  const int row = blockIdx.x*64 + w*16 + (l & 15);
  const int mo = l & 15;
  const int ko = (l>>4)*8;
  floatx4 acc = {};
  const __hip_bfloat16* Ap = pairP + (size_t)j*1048576 + (size_t)row*256;
  const __hip_bfloat16* Bp = Bp3 + (size_t)j*4608 + mo*288;
  #pragma unroll
  for(int kc=0; kc<8; kc++){
    short8 a = *(const short8*)(Ap + kc*32 + ko);
    short8 b = *(const short8*)(Bp + kc*32 + ko);
    acc = __builtin_amdgcn_mfma_f32_16x16x32_bf16(a, b, acc, 0, 0, 0);
  }
  {
    short8 a = *(const short8*)(h2P + (size_t)j*131072 + (size_t)row*32 + ko);
    short8 b = *(const short8*)(Bp + 256 + ko);
    acc = __builtin_amdgcn_mfma_f32_16x16x32_bf16(a, b, acc, 0, 0, 0);
  }
  if(mo < 9){
    #pragma unroll
    for(int r=0; r<4; r++){
      int b = blockIdx.x*64 + w*16 + (l>>4)*4 + r;
      out[((size_t)b*9 + mo)*8 + j] = (acc[r] + ((j==0) ? b3l[mo] : 0.f)) * INV_SQRT2F;
    }
  }
}

// ---------------- launch ----------------
extern "C" void kernel_launch(void* const* d_in, const int* in_sizes, int n_in,
                              void* d_out, int out_size, void* d_ws, size_t ws_size,
                              hipStream_t stream){
  const float* x        = (const float*)d_in[0];
  const float* w_right1 = (const float*)d_in[1];
  const float* norm_a1  = (const float*)d_in[2];
  const float* w_left1  = (const float*)d_in[3];
  const float* b_left1  = (const float*)d_in[4];
  const float* gp_w1    = (const float*)d_in[5];
  const float* silu_a   = (const float*)d_in[6];
  const float* silu_b   = (const float*)d_in[7];
  const float* w_right2 = (const float*)d_in[8];
  const float* norm_a2  = (const float*)d_in[9];
  const float* w_left2  = (const float*)d_in[10];
  const float* b_left2  = (const float*)d_in[11];
  const float* gp_w2    = (const float*)d_in[12];
  const float* w_right3 = (const float*)d_in[13];
  const float* norm_a3  = (const float*)d_in[14];
  const float* w_left3  = (const float*)d_in[15];
  const float* b_left3  = (const float*)d_in[16];
  const float* gp_w3    = (const float*)d_in[17];
  float* out = (float*)d_out;

  char* wsb = (char*)d_ws;
  __hip_bfloat16* xP    = (__hip_bfloat16*)wsb;
  __hip_bfloat16* xrI   = (__hip_bfloat16*)wsb;
  __hip_bfloat16* pairP = (__hip_bfloat16*)wsb;
  float*          linr2 = (float*)(wsb + 16777216);
  float*          left2 = (float*)(wsb + 20971520);
  float*          h2f   = (float*)(wsb + 25165824);
  __hip_bfloat16* h2P   = (__hip_bfloat16*)(wsb + 29360128);
  __hip_bfloat16* wP    = (__hip_bfloat16*)(wsb + 33554432);
  __hip_bfloat16* h1P   = (__hip_bfloat16*)(wsb + 33554432);
  float*          h1s   = (float*)(wsb + 35651584);
  __hip_bfloat16* linrP = (__hip_bfloat16*)(wsb + 41943040);
  float*          h1part= (float*)(wsb + 41943040);
  float*          linr3 = (float*)(wsb + 41943040);
  __hip_bfloat16* Bpack = (__hip_bfloat16*)(wsb + 75497472);
  __hip_bfloat16* wlP   = (__hip_bfloat16*)(wsb + 77594624);
  float*          leftB = (float*)(wsb + 77856768);
  __hip_bfloat16* w2rP  = (__hip_bfloat16*)(wsb + 82051072);
  __hip_bfloat16* w2lP  = (__hip_bfloat16*)(wsb + 82051072 + 16384);
  __hip_bfloat16* w3rP  = (__hip_bfloat16*)(wsb + 82051072 + 32768);
  __hip_bfloat16* Bp3   = (__hip_bfloat16*)(wsb + 82051072 + 49152);

  pack_all<<<10480, 256, 0, stream>>>(x, w_right1, gp_w1, w_left1,
                                      w_right2, w_left2, w_right3, gp_w3, w_left3,
                                      xP, wP, Bpack, wlP, w2rP, w2lP, w3rP, Bp3);
  k1_mfma<<<dim3(32, 4, 8), 256, 0, stream>>>(xP, wP, linrP);
  k_left<<<dim3(64, 8), 256, 0, stream>>>(xP, wlP, leftB);
  knorm<<<1024, 256, 0, stream>>>(linrP, norm_a1, xrI);
  k2_mfma<<<dim3(64, 8), 256, 0, stream>>>(x, xrI, Bpack, h1part);
  k2b_silu<<<512, 256, 0, stream>>>(h1part, leftB, b_left1, silu_a, silu_b, h1s, h1P);
  k3a<<<dim3(64, 8), 256, 0, stream>>>(h1P, w2rP, w2lP, linr2, left2);
  k3b<<<512, 256, 0, stream>>>(linr2, left2, h1s, norm_a2, gp_w2, b_left2,
                               silu_a, silu_b, h2f, h2P);
  k3c<<<dim3(64, 8), 256, 0, stream>>>(h2P, w3rP, linr3);
  k3d<<<512, 256, 0, stream>>>(linr3, h2f, norm_a3, pairP);
  k3e<<<dim3(64, 8), 256, 0, stream>>>(pairP, h2P, Bp3, b_left3, out);
}

// Round 14
// 140.728 us; speedup vs baseline: 1.2246x; 1.0302x over previous
//
#include <hip/hip_runtime.h>
#include <hip/hip_bf16.h>
#include <math.h>

#define INV_SQRT2F 0.70710678118654752440f
#define AS1 __attribute__((address_space(1)))
#define AS3 __attribute__((address_space(3)))

typedef __attribute__((ext_vector_type(8))) short short8;
typedef __attribute__((ext_vector_type(4))) float floatx4;

// ---------------- compile-time algebra tables ----------------
struct Tables {
  int   kof[8][8];
  float cs[8][8];
  int   widx[8][8];
};
constexpr int t_bm(int i){ constexpr int t[8] = {0,1,2,4,3,5,6,7}; return t[i]; }
constexpr int t_idx(int b){ constexpr int t[8] = {0,1,2,4,3,5,6,7}; return t[b]; }
constexpr int t_gr(int i){ constexpr int t[8] = {0,1,1,1,2,2,2,3}; return t[i]; }
constexpr int t_pc(int x){ int c=0; while(x){ c += x&1; x >>= 1; } return c; }
constexpr float t_sign(int a, int b){
  float s = 1.f; int aa = a >> 1;
  while(aa){ if(t_pc(aa & b) & 1) s = -s; aa >>= 1; }
  return s;
}
constexpr int   c_kof(int j,int i){ return t_idx(t_bm(i)^t_bm(j)); }
constexpr float c_cs(int j,int i){ return t_sign(t_bm(i), t_bm(c_kof(j,i))); }
constexpr int   c_widx(int j,int i){ return t_gr(i)*16 + t_gr(j)*4 + t_gr(c_kof(j,i)); }
constexpr Tables mkTables(){
  Tables T{};
  for(int j=0;j<8;j++) for(int i=0;i<8;i++){
    T.kof[j][i]  = c_kof(j,i);
    T.cs[j][i]   = c_cs(j,i);
    T.widx[j][i] = c_widx(j,i);
  }
  return T;
}
__device__ const Tables d_TB = mkTables();

__device__ __forceinline__ float rcpf(float v){ return __builtin_amdgcn_rcpf(v); }
__device__ __forceinline__ float sigf(float z){ return rcpf(1.f + __expf(-z)); }
__device__ __forceinline__ int gradeOfIdx(int i){ return (i==0)?0:((i<4)?1:((i<7)?2:3)); }
__device__ __forceinline__ short f2bf(float v){
  __hip_bfloat16 h = __float2bfloat16(v);
  short s; __builtin_memcpy(&s, &h, 2); return s;
}
__device__ __forceinline__ float bf2f(short s){
  unsigned int w = ((unsigned int)(unsigned short)s) << 16;
  float f; __builtin_memcpy(&f, &w, 4); return f;
}
__device__ __forceinline__ void norm8v(float* v, float4 na){
  float s0 = sigf(na.x)*(fabsf(v[0])-1.f)+1.f+1e-6f;
  float s1 = sigf(na.y)*(sqrtf(v[1]*v[1]+v[2]*v[2]+v[3]*v[3])-1.f)+1.f+1e-6f;
  float s2 = sigf(na.z)*(sqrtf(v[4]*v[4]+v[5]*v[5]+v[6]*v[6])-1.f)+1.f+1e-6f;
  float s3 = sigf(na.w)*(fabsf(v[7])-1.f)+1.f+1e-6f;
  float r0 = rcpf(s0), r1 = rcpf(s1), r2 = rcpf(s2), r3 = rcpf(s3);
  v[0]*=r0; v[1]*=r1; v[2]*=r1; v[3]*=r1; v[4]*=r2; v[5]*=r2; v[6]*=r2; v[7]*=r3;
}

// ---------------- pack_all: pack_x (bx<8192) + weight packs ----------------
__global__ __launch_bounds__(256) void pack_all(const float* __restrict__ x,
                                                const float* __restrict__ w,
                                                const float* __restrict__ gpw,
                                                const float* __restrict__ wl,
                                                const float* __restrict__ w2r,
                                                const float* __restrict__ w2l,
                                                const float* __restrict__ w3r,
                                                const float* __restrict__ gw3,
                                                const float* __restrict__ w3l,
                                                __hip_bfloat16* __restrict__ xP,
                                                __hip_bfloat16* __restrict__ wP,
                                                __hip_bfloat16* __restrict__ Bpack,
                                                __hip_bfloat16* __restrict__ wlP,
                                                __hip_bfloat16* __restrict__ w2rP,
                                                __hip_bfloat16* __restrict__ w2lP,
                                                __hip_bfloat16* __restrict__ w3rP,
                                                __hip_bfloat16* __restrict__ Bp3){
  const int bx = blockIdx.x;
  if(bx < 8192){
    size_t e = (size_t)bx*256 + threadIdx.x;
    float4 u0 = *(const float4*)(x + e*8);
    float4 u1 = *(const float4*)(x + e*8 + 4);
    float u[8] = {u0.x,u0.y,u0.z,u0.w,u1.x,u1.y,u1.z,u1.w};
    #pragma unroll
    for(int i=0;i<8;i++) xP[(size_t)i*2097152 + e] = __float2bfloat16(u[i]);
  } else if(bx < 9216){
    size_t e = (size_t)(bx-8192)*256 + threadIdx.x;
    float4 u = *(const float4*)(w + e*4);
    float v[4] = {u.x,u.y,u.z,u.w};
    #pragma unroll
    for(int g=0; g<4; g++) wP[(size_t)g*262144 + e] = __float2bfloat16(v[g]);
  } else if(bx < 9728){
    int t = (bx-9216)*256 + threadIdx.x;          // j*16384 + n*32 + m
    int j = t >> 14; int n = (t >> 5) & 511; int m = t & 31;
    const float* src = gpw + ((size_t)m*512 + n)*64;
    short8 o;
    #pragma unroll
    for(int jj=0; jj<8; jj++){
      if(jj == j){
        #pragma unroll
        for(int i=0;i<8;i++) o[i] = f2bf(c_cs(jj,i) * src[c_widx(jj,i)]);
      }
    }
    int q = n & 3;
    *(short8*)(Bpack + (size_t)(n>>2)*8192 + j*1024 + q*256 + m*8) = o;
  } else if(bx < 10240){
    int t2 = (bx-9728)*256 + threadIdx.x;         // j*16384 + m*512 + n
    int j = t2 >> 14; int m = (t2 >> 9) & 31; int n = t2 & 511;
    int g = gradeOfIdx(j);
    wlP[t2] = __float2bfloat16(wl[((size_t)m*512 + n)*4 + g]);
  } else if(bx < 10336){
    int t = (bx-10240)*256 + threadIdx.x;
    int which = t >> 13; int r = t & 8191;
    int j = r >> 10; int n = (r >> 5) & 31; int m = r & 31;
    int g = gradeOfIdx(j);
    const float* src = (which==0) ? w2r : (which==1) ? w2l : w3r;
    __hip_bfloat16* dst = (which==0) ? w2rP : (which==1) ? w2lP : w3rP;
    dst[r] = __float2bfloat16(src[((size_t)n*32 + m)*4 + g]);
  } else {
    int t2 = (bx-10336)*256 + threadIdx.x;        // j*4608 + mo*288 + k
    if(t2 >= 36864) return;
    int j = t2 / 4608; int rem = t2 - j*4608;
    int mo = rem / 288; int k = rem - mo*288;
    float v = 0.f;
    if(mo < 9){
      if(k < 256){
        int n = k >> 3, i = k & 7;
        v = d_TB.cs[j][i] * gw3[((size_t)mo*32 + n)*64 + d_TB.widx[j][i]];
      } else {
        int n = k - 256;
        v = w3l[((size_t)mo*32 + n)*4 + gradeOfIdx(j)];
      }
    }
    Bp3[t2] = __float2bfloat16(v);
  }
}

// ---------------- K1 MFMA: linrP[i][b][n] = sum_m xP[i][b][m] * wP[g(i)][n][m] ----------------
// BM=128, BN=128, BK=64; grid (32,4,8)
__global__ __launch_bounds__(256) void k1_mfma(const __hip_bfloat16* __restrict__ xP,
                                               const __hip_bfloat16* __restrict__ wP,
                                               __hip_bfloat16* __restrict__ linrP){
  __shared__ __align__(16) char lds[32768];
  char* As = lds;
  char* Bs = lds + 16384;
  const int tid = threadIdx.x;
  const int l   = tid & 63;
  const int w   = tid >> 6;
  const int i   = blockIdx.z;
  const int g   = gradeOfIdx(i);
  const size_t b0 = (size_t)blockIdx.x * 128;
  const size_t n0 = (size_t)blockIdx.y * 128;
  const __hip_bfloat16* Ag = xP + (size_t)i*2097152;
  const __hip_bfloat16* Bg = wP + (size_t)g*262144;

  const int wave_m = (w & 1) * 64;
  const int wave_n = (w >> 1) * 64;
  const int srow = l >> 3;
  const int scol = ((l & 7) ^ srow) * 8;

  floatx4 acc[4][4] = {};

  for(int kt = 0; kt < 512; kt += 64){
    #pragma unroll
    for(int it=0; it<4; it++){
      int c   = it*4 + w;
      int row = c*8 + srow;
      const __hip_bfloat16* sa = Ag + (b0 + row)*512 + kt + scol;
      const __hip_bfloat16* sb = Bg + (n0 + row)*512 + kt + scol;
      __builtin_amdgcn_global_load_lds((const AS1 void*)sa, (AS3 void*)(As + c*1024 + l*16), 16, 0, 0);
      __builtin_amdgcn_global_load_lds((const AS1 void*)sb, (AS3 void*)(Bs + c*1024 + l*16), 16, 0, 0);
    }
    __syncthreads();
    #pragma unroll
    for(int ks=0; ks<2; ks++){
      short8 af[4], bf[4];
      #pragma unroll
      for(int f=0; f<4; f++){
        int rA = wave_m + f*16 + (l & 15);
        int ca = (ks*64 + (l>>4)*16) ^ ((rA & 7) << 4);
        af[f] = *(const short8*)(As + rA*128 + ca);
        int rB = wave_n + f*16 + (l & 15);
        int cb = (ks*64 + (l>>4)*16) ^ ((rB & 7) << 4);
        bf[f] = *(const short8*)(Bs + rB*128 + cb);
      }
      #pragma unroll
      for(int mf=0; mf<4; mf++){
        #pragma unroll
        for(int nf=0; nf<4; nf++){
          acc[mf][nf] = __builtin_amdgcn_mfma_f32_16x16x32_bf16(af[mf], bf[nf], acc[mf][nf], 0, 0, 0);
        }
      }
    }
    __syncthreads();
  }
  __hip_bfloat16* outp = linrP + (size_t)i*2097152;
  #pragma unroll
  for(int mf=0; mf<4; mf++){
    #pragma unroll
    for(int nf=0; nf<4; nf++){
      #pragma unroll
      for(int r=0; r<4; r++){
        size_t m = wave_m + mf*16 + ((l>>4)<<2) + r;
        size_t n = wave_n + nf*16 + (l & 15);
        outp[(b0+m)*512 + n0+n] = __float2bfloat16(acc[mf][nf][r]);
      }
    }
  }
}

// ---------------- k_ln: fused k_left (bx<512) + knorm (bx>=512) ----------------
// Both consume k1/pack outputs and are independent: co-scheduling hides
// k_left's MFMA latency under knorm's BW streaming, saves one launch gap.
__global__ __launch_bounds__(256) void k_ln(const __hip_bfloat16* __restrict__ xP,
                                            const __hip_bfloat16* __restrict__ wlP,
                                            float* __restrict__ leftB,
                                            const __hip_bfloat16* __restrict__ linrP,
                                            const float* __restrict__ norm_a,
                                            __hip_bfloat16* __restrict__ xrI){
  const int bx = blockIdx.x;
  if(bx < 512){
    // ---- k_left body: leftB[j][b][m] = sum_n xP[j][b][n]*wlP[j][m][n] ----
    const int tid = threadIdx.x;
    const int l = tid & 63, w = tid >> 6;
    const int j = bx >> 6;                 // 8 j x 64 bx-blocks
    const int bxl = bx & 63;
    const int row = bxl*64 + w*16 + (l & 15);
    floatx4 acc[2] = {};
    const __hip_bfloat16* Ap = xP + (size_t)j*2097152;
    const __hip_bfloat16* Wp = wlP + (size_t)j*16384;
    for(int nc=0; nc<16; nc++){
      int nb = nc*32 + (l>>4)*8;
      short8 a  = *(const short8*)(Ap + (size_t)row*512 + nb);
      short8 b0 = *(const short8*)(Wp + (l&15)*512 + nb);
      short8 b1 = *(const short8*)(Wp + ((l&15)+16)*512 + nb);
      acc[0] = __builtin_amdgcn_mfma_f32_16x16x32_bf16(a, b0, acc[0], 0, 0, 0);
      acc[1] = __builtin_amdgcn_mfma_f32_16x16x32_bf16(a, b1, acc[1], 0, 0, 0);
    }
    #pragma unroll
    for(int mf=0; mf<2; mf++){
      #pragma unroll
      for(int r=0; r<4; r++){
        int b = bxl*64 + w*16 + (l>>4)*4 + r;
        leftB[(size_t)j*131072 + b*32 + mf*16 + (l&15)] = acc[mf][r];
      }
    }
  } else {
    // ---- knorm body: normalize linrP planes -> xrI interleaved bf16 [e][k] ----
    const size_t base = ((size_t)(bx-512)*256 + threadIdx.x) * 8;
    const short* lp = (const short*)linrP;
    short8 v[8];
    #pragma unroll
    for(int i=0;i<8;i++) v[i] = *(const short8*)(lp + (size_t)i*2097152 + base);
    short8 o[8];
    #pragma unroll
    for(int s=0;s<8;s++){
      float u[8];
      #pragma unroll
      for(int i=0;i<8;i++) u[i] = bf2f(v[i][s]);
      int n = (int)((base + s) & 511);
      float4 na = *(const float4*)(norm_a + n*4);
      norm8v(u, na);
      #pragma unroll
      for(int i=0;i<8;i++) o[s][i] = f2bf(u[i]);
    }
    short* op = (short*)xrI;
    #pragma unroll
    for(int s=0;s<8;s++) *(short8*)(op + (base+s)*8) = o[s];
  }
}

// ---------------- k2_mfma: fcgp1 product; 2 Bpack chunks per barrier (BK-doubled) ----------------
__global__ __launch_bounds__(256) void k2_mfma(const float* __restrict__ x,
                                               const __hip_bfloat16* __restrict__ xrI,
                                               const __hip_bfloat16* __restrict__ Bpack,
                                               float* __restrict__ h1part){
  __shared__ __align__(16) char bsh[65536];
  const int tid = threadIdx.x;
  const int l = tid & 63, w = tid >> 6;
  const int row = blockIdx.x*64 + w*16 + (l & 15);
  const int nsb = blockIdx.y * 64;
  const int boffB = (l>>4)*512 + (l&15)*16;
  floatx4 acc[8][2] = {};

  const char* base = (const char*)(Bpack + (size_t)(blockIdx.y*16)*8192);
  #pragma unroll
  for(int it=0; it<8; it++){
    int off = (it*256 + tid)*16;
    __builtin_amdgcn_global_load_lds((const AS1 void*)(base + off), (AS3 void*)(bsh + off), 16, 0, 0);
  }
  __syncthreads();

  for(int p = 0; p < 8; p++){
    if(p < 7){
      const char* src = base + (size_t)(p+1)*32768;
      char* dst = bsh + ((p+1)&1)*32768;
      #pragma unroll
      for(int it=0; it<8; it++){
        int off = (it*256 + tid)*16;
        __builtin_amdgcn_global_load_lds((const AS1 void*)(src + off), (AS3 void*)(dst + off), 16, 0, 0);
      }
    }
    const char* bufp = bsh + (p&1)*32768;
    #pragma unroll
    for(int sub=0; sub<2; sub++){
      const int nc = p*2 + sub;
      const int n = nsb + nc*4 + (l>>4);
      const size_t e = (size_t)row*512 + n;
      float4 xa = *(const float4*)(x + e*8);
      float4 xb = *(const float4*)(x + e*8 + 4);
      float xv[8] = {xa.x,xa.y,xa.z,xa.w,xb.x,xb.y,xb.z,xb.w};
      short8 xri = *(const short8*)((const short*)xrI + e*8);
      float xr[8];
      #pragma unroll
      for(int i=0;i<8;i++) xr[i] = bf2f(xri[i]);
      const char* bcur = bufp + sub*16384;
      #pragma unroll
      for(int j=0;j<8;j++){
        short8 af;
        #pragma unroll
        for(int i=0;i<8;i++) af[i] = f2bf(xv[i] * xr[c_kof(j,i)]);
        short8 b0 = *(const short8*)(bcur + j*2048 + boffB);
        short8 b1 = *(const short8*)(bcur + j*2048 + boffB + 256);
        acc[j][0] = __builtin_amdgcn_mfma_f32_16x16x32_bf16(af, b0, acc[j][0], 0, 0, 0);
        acc[j][1] = __builtin_amdgcn_mfma_f32_16x16x32_bf16(af, b1, acc[j][1], 0, 0, 0);
      }
    }
    __syncthreads();
  }
  const int sp = blockIdx.y;
  #pragma unroll
  for(int j=0;j<8;j++){
    #pragma unroll
    for(int mf=0; mf<2; mf++){
      #pragma unroll
      for(int r=0; r<4; r++){
        int b = blockIdx.x*64 + w*16 + (l>>4)*4 + r;
        h1part[((size_t)(sp*8+j))*131072 + b*32 + mf*16 + (l&15)] = acc[j][mf][r];
      }
    }
  }
}

// ---------------- K2b: reduce + left + bias + silu -> h1s f32 + h1P bf16 planes ----------------
__global__ __launch_bounds__(256) void k2b_silu(const float* __restrict__ h1part,
                                                const float* __restrict__ leftB,
                                                const float* __restrict__ bl,
                                                const float* __restrict__ sa,
                                                const float* __restrict__ sb,
                                                float* __restrict__ h1s,
                                                __hip_bfloat16* __restrict__ h1P){
  int idx = blockIdx.x*256 + threadIdx.x;  // b*32+m
  int m = idx & 31;
  float v[8];
  #pragma unroll
  for(int j=0;j<8;j++){
    float s = leftB[(size_t)j*131072 + idx];
    #pragma unroll
    for(int sp=0; sp<8; sp++) s += h1part[((size_t)(sp*8+j))*131072 + idx];
    v[j] = s;
  }
  v[0] += bl[m];
  #pragma unroll
  for(int i=0;i<8;i++) v[i] *= INV_SQRT2F;
  float q1 = v[1]*v[1]+v[2]*v[2]+v[3]*v[3];
  float q2 = v[4]*v[4]+v[5]*v[5]+v[6]*v[6];
  float q3 = v[7]*v[7];
  float4 sa4 = *(const float4*)&sa[m*4];
  float4 sb4 = *(const float4*)&sb[m*4];
  float g0 = sigf(sa4.x*v[0] + sb4.x);
  float g1 = sigf(sa4.y*q1   + sb4.y);
  float g2 = sigf(sa4.z*q2   + sb4.z);
  float g3 = sigf(sa4.w*q3   + sb4.w);
  float o[8] = {g0*v[0], g1*v[1], g1*v[2], g1*v[3], g2*v[4], g2*v[5], g2*v[6], g3*v[7]};
  *(float4*)&h1s[(size_t)idx*8]     = make_float4(o[0],o[1],o[2],o[3]);
  *(float4*)&h1s[(size_t)idx*8 + 4] = make_float4(o[4],o[5],o[6],o[7]);
  #pragma unroll
  for(int j=0;j<8;j++) h1P[(size_t)j*131072 + idx] = __float2bfloat16(o[j]);
}

// ---------------- k3a: linr2/left2 [j][b][n] = sum_m h1P[j][b][m] * w2{r,l}P[j][n][m] ----------------
__global__ __launch_bounds__(256) void k3a(const __hip_bfloat16* __restrict__ h1P,
                                           const __hip_bfloat16* __restrict__ w2rP,
                                           const __hip_bfloat16* __restrict__ w2lP,
                                           float* __restrict__ linr2,
                                           float* __restrict__ left2){
  const int tid = threadIdx.x;
  const int l = tid & 63, w = tid >> 6;
  const int j = blockIdx.y;
  const int row = blockIdx.x*64 + w*16 + (l & 15);
  const int ko = (l>>4)*8;
  short8 a   = *(const short8*)(h1P + (size_t)j*131072 + (size_t)row*32 + ko);
  short8 br0 = *(const short8*)(w2rP + j*1024 + (l&15)*32 + ko);
  short8 br1 = *(const short8*)(w2rP + j*1024 + ((l&15)+16)*32 + ko);
  short8 bl0 = *(const short8*)(w2lP + j*1024 + (l&15)*32 + ko);
  short8 bl1 = *(const short8*)(w2lP + j*1024 + ((l&15)+16)*32 + ko);
  floatx4 aR0 = {}, aR1 = {}, aL0 = {}, aL1 = {};
  aR0 = __builtin_amdgcn_mfma_f32_16x16x32_bf16(a, br0, aR0, 0, 0, 0);
  aR1 = __builtin_amdgcn_mfma_f32_16x16x32_bf16(a, br1, aR1, 0, 0, 0);
  aL0 = __builtin_amdgcn_mfma_f32_16x16x32_bf16(a, bl0, aL0, 0, 0, 0);
  aL1 = __builtin_amdgcn_mfma_f32_16x16x32_bf16(a, bl1, aL1, 0, 0, 0);
  #pragma unroll
  for(int r=0; r<4; r++){
    int b = blockIdx.x*64 + w*16 + (l>>4)*4 + r;
    linr2[(size_t)j*131072 + b*32 + (l&15)]      = aR0[r];
    linr2[(size_t)j*131072 + b*32 + 16 + (l&15)] = aR1[r];
    left2[(size_t)j*131072 + b*32 + (l&15)]      = aL0[r];
    left2[(size_t)j*131072 + b*32 + 16 + (l&15)] = aL1[r];
  }
}

// ---------------- k3b: norm(linr2) -> x2; sgp + left2 + bias + silu -> h2f, h2P ----------------
__global__ __launch_bounds__(256) void k3b(const float* __restrict__ linr2,
                                           const float* __restrict__ left2,
                                           const float* __restrict__ h1s,
                                           const float* __restrict__ na2,
                                           const float* __restrict__ gw2,
                                           const float* __restrict__ b2l,
                                           const float* __restrict__ sa,
                                           const float* __restrict__ sb,
                                           float* __restrict__ h2f,
                                           __hip_bfloat16* __restrict__ h2P){
  __shared__ float g2s[32][65];
  {
    const float4* src = (const float4*)gw2;
    #pragma unroll
    for(int r=0; r<2; r++){
      int t = threadIdx.x + r*256;
      float4 v = src[t];
      int n = t >> 4;
      int c = (t & 15) * 4;
      g2s[n][c]=v.x; g2s[n][c+1]=v.y; g2s[n][c+2]=v.z; g2s[n][c+3]=v.w;
    }
  }
  __syncthreads();
  int idx = blockIdx.x*256 + threadIdx.x;  // b*32+n
  int n = idx & 31;
  float x2[8];
  #pragma unroll
  for(int j=0;j<8;j++) x2[j] = linr2[(size_t)j*131072 + idx];
  norm8v(x2, *(const float4*)&na2[n*4]);
  float4 h0 = *(const float4*)&h1s[(size_t)idx*8];
  float4 h1 = *(const float4*)&h1s[(size_t)idx*8 + 4];
  float h[8] = {h0.x,h0.y,h0.z,h0.w,h1.x,h1.y,h1.z,h1.w};
  float v[8];
  #pragma unroll
  for(int j=0;j<8;j++){
    float pr = 0.f;
    #pragma unroll
    for(int i=0;i<8;i++)
      pr = fmaf(c_cs(j,i) * h[i] * x2[c_kof(j,i)], g2s[n][c_widx(j,i)], pr);
    v[j] = (pr + left2[(size_t)j*131072 + idx] + ((j==0) ? b2l[n] : 0.f)) * INV_SQRT2F;
  }
  float q1 = v[1]*v[1]+v[2]*v[2]+v[3]*v[3];
  float q2 = v[4]*v[4]+v[5]*v[5]+v[6]*v[6];
  float q3 = v[7]*v[7];
  float4 sa4 = *(const float4*)&sa[n*4];
  float4 sb4 = *(const float4*)&sb[n*4];
  float g0 = sigf(sa4.x*v[0] + sb4.x);
  float g1 = sigf(sa4.y*q1   + sb4.y);
  float gg2 = sigf(sa4.z*q2  + sb4.z);
  float g3 = sigf(sa4.w*q3   + sb4.w);
  float o[8] = {g0*v[0], g1*v[1], g1*v[2], g1*v[3], gg2*v[4], gg2*v[5], gg2*v[6], g3*v[7]};
  *(float4*)&h2f[(size_t)idx*8]     = make_float4(o[0],o[1],o[2],o[3]);
  *(float4*)&h2f[(size_t)idx*8 + 4] = make_float4(o[4],o[5],o[6],o[7]);
  #pragma unroll
  for(int j=0;j<8;j++) h2P[(size_t)j*131072 + idx] = __float2bfloat16(o[j]);
}

// ---------------- k3c: linr3[j][b][n] = sum_m h2P[j][b][m] * w3rP[j][n][m] ----------------
__global__ __launch_bounds__(256) void k3c(const __hip_bfloat16* __restrict__ h2P,
                                           const __hip_bfloat16* __restrict__ w3rP,
                                           float* __restrict__ linr3){
  const int tid = threadIdx.x;
  const int l = tid & 63, w = tid >> 6;
  const int j = blockIdx.y;
  const int row = blockIdx.x*64 + w*16 + (l & 15);
  const int ko = (l>>4)*8;
  short8 a   = *(const short8*)(h2P + (size_t)j*131072 + (size_t)row*32 + ko);
  short8 b0  = *(const short8*)(w3rP + j*1024 + (l&15)*32 + ko);
  short8 b1  = *(const short8*)(w3rP + j*1024 + ((l&15)+16)*32 + ko);
  floatx4 a0 = {}, a1 = {};
  a0 = __builtin_amdgcn_mfma_f32_16x16x32_bf16(a, b0, a0, 0, 0, 0);
  a1 = __builtin_amdgcn_mfma_f32_16x16x32_bf16(a, b1, a1, 0, 0, 0);
  #pragma unroll
  for(int r=0; r<4; r++){
    int b = blockIdx.x*64 + w*16 + (l>>4)*4 + r;
    linr3[(size_t)j*131072 + b*32 + (l&15)]      = a0[r];
    linr3[(size_t)j*131072 + b*32 + 16 + (l&15)] = a1[r];
  }
}

// ---------------- k3d: norm(linr3) -> x3; pairP[j][b][n*8+i] = bf16(h2[i]*x3[kof(j,i)]) ----------------
__global__ __launch_bounds__(256) void k3d(const float* __restrict__ linr3,
                                           const float* __restrict__ h2f,
                                           const float* __restrict__ na3,
                                           __hip_bfloat16* __restrict__ pairP){
  int idx = blockIdx.x*256 + threadIdx.x;  // b*32+n
  int n = idx & 31;
  float x3[8];
  #pragma unroll
  for(int j=0;j<8;j++) x3[j] = linr3[(size_t)j*131072 + idx];
  norm8v(x3, *(const float4*)&na3[n*4]);
  float4 h0 = *(const float4*)&h2f[(size_t)idx*8];
  float4 h1 = *(const float4*)&h2f[(size_t)idx*8 + 4];
  float h[8] = {h0.x,h0.y,h0.z,h0.w,h1.x,h1.y,h1.z,h1.w};
  #pragma unroll
  for(int j=0;j<8;j++){
    short8 o;
    #pragma unroll
    for(int i=0;i<8;i++) o[i] = f2bf(h[i] * x3[c_kof(j,i)]);
    *(short8*)(pairP + (size_t)j*1048576 + (size_t)idx*8) = o;
  }
}

// ---------------- k3e: out[b][mo][j] = (sum_k pair/h2 x Bp3 + bias) * c ----------------
__global__ __launch_bounds__(256) void k3e(const __hip_bfloat16* __restrict__ pairP,
                                           const __hip_bfloat16* __restrict__ h2P,
                                           const __hip_bfloat16* __restrict__ Bp3,
                                           const float* __restrict__ b3l,
                                           float* __restrict__ out){
  const int tid = threadIdx.x;
  const int l = tid & 63, w = tid >> 6;
  const int j = blockIdx.y;
  const int row = blockIdx.x*64 + w*16 + (l & 15);
  const int mo = l & 15;
  const int ko = (l>>4)*8;
  floatx4 acc = {};
  const __hip_bfloat16* Ap = pairP + (size_t)j*1048576 + (size_t)row*256;
  const __hip_bfloat16* Bp = Bp3 + (size_t)j*4608 + mo*288;
  #pragma unroll
  for(int kc=0; kc<8; kc++){
    short8 a = *(const short8*)(Ap + kc*32 + ko);
    short8 b = *(const short8*)(Bp + kc*32 + ko);
    acc = __builtin_amdgcn_mfma_f32_16x16x32_bf16(a, b, acc, 0, 0, 0);
  }
  {
    short8 a = *(const short8*)(h2P + (size_t)j*131072 + (size_t)row*32 + ko);
    short8 b = *(const short8*)(Bp + 256 + ko);
    acc = __builtin_amdgcn_mfma_f32_16x16x32_bf16(a, b, acc, 0, 0, 0);
  }
  if(mo < 9){
    #pragma unroll
    for(int r=0; r<4; r++){
      int b = blockIdx.x*64 + w*16 + (l>>4)*4 + r;
      out[((size_t)b*9 + mo)*8 + j] = (acc[r] + ((j==0) ? b3l[mo] : 0.f)) * INV_SQRT2F;
    }
  }
}

// ---------------- launch ----------------
extern "C" void kernel_launch(void* const* d_in, const int* in_sizes, int n_in,
                              void* d_out, int out_size, void* d_ws, size_t ws_size,
                              hipStream_t stream){
  const float* x        = (const float*)d_in[0];
  const float* w_right1 = (const float*)d_in[1];
  const float* norm_a1  = (const float*)d_in[2];
  const float* w_left1  = (const float*)d_in[3];
  const float* b_left1  = (const float*)d_in[4];
  const float* gp_w1    = (const float*)d_in[5];
  const float* silu_a   = (const float*)d_in[6];
  const float* silu_b   = (const float*)d_in[7];
  const float* w_right2 = (const float*)d_in[8];
  const float* norm_a2  = (const float*)d_in[9];
  const float* w_left2  = (const float*)d_in[10];
  const float* b_left2  = (const float*)d_in[11];
  const float* gp_w2    = (const float*)d_in[12];
  const float* w_right3 = (const float*)d_in[13];
  const float* norm_a3  = (const float*)d_in[14];
  const float* w_left3  = (const float*)d_in[15];
  const float* b_left3  = (const float*)d_in[16];
  const float* gp_w3    = (const float*)d_in[17];
  float* out = (float*)d_out;

  char* wsb = (char*)d_ws;
  __hip_bfloat16* xP    = (__hip_bfloat16*)wsb;
  __hip_bfloat16* xrI   = (__hip_bfloat16*)wsb;
  __hip_bfloat16* pairP = (__hip_bfloat16*)wsb;
  float*          linr2 = (float*)(wsb + 16777216);
  float*          left2 = (float*)(wsb + 20971520);
  float*          h2f   = (float*)(wsb + 25165824);
  __hip_bfloat16* h2P   = (__hip_bfloat16*)(wsb + 29360128);
  __hip_bfloat16* wP    = (__hip_bfloat16*)(wsb + 33554432);
  __hip_bfloat16* h1P   = (__hip_bfloat16*)(wsb + 33554432);
  float*          h1s   = (float*)(wsb + 35651584);
  __hip_bfloat16* linrP = (__hip_bfloat16*)(wsb + 41943040);
  float*          h1part= (float*)(wsb + 41943040);
  float*          linr3 = (float*)(wsb + 41943040);
  __hip_bfloat16* Bpack = (__hip_bfloat16*)(wsb + 75497472);
  __hip_bfloat16* wlP   = (__hip_bfloat16*)(wsb + 77594624);
  float*          leftB = (float*)(wsb + 77856768);
  __hip_bfloat16* w2rP  = (__hip_bfloat16*)(wsb + 82051072);
  __hip_bfloat16* w2lP  = (__hip_bfloat16*)(wsb + 82051072 + 16384);
  __hip_bfloat16* w3rP  = (__hip_bfloat16*)(wsb + 82051072 + 32768);
  __hip_bfloat16* Bp3   = (__hip_bfloat16*)(wsb + 82051072 + 49152);

  pack_all<<<10480, 256, 0, stream>>>(x, w_right1, gp_w1, w_left1,
                                      w_right2, w_left2, w_right3, gp_w3, w_left3,
                                      xP, wP, Bpack, wlP, w2rP, w2lP, w3rP, Bp3);
  k1_mfma<<<dim3(32, 4, 8), 256, 0, stream>>>(xP, wP, linrP);
  k_ln<<<1536, 256, 0, stream>>>(xP, wlP, leftB, linrP, norm_a1, xrI);
  k2_mfma<<<dim3(64, 8), 256, 0, stream>>>(x, xrI, Bpack, h1part);
  k2b_silu<<<512, 256, 0, stream>>>(h1part, leftB, b_left1, silu_a, silu_b, h1s, h1P);
  k3a<<<dim3(64, 8), 256, 0, stream>>>(h1P, w2rP, w2lP, linr2, left2);
  k3b<<<512, 256, 0, stream>>>(linr2, left2, h1s, norm_a2, gp_w2, b_left2,
                               silu_a, silu_b, h2f, h2P);
  k3c<<<dim3(64, 8), 256, 0, stream>>>(h2P, w3rP, linr3);
  k3d<<<512, 256, 0, stream>>>(linr3, h2f, norm_a3, pairP);
  k3e<<<dim3(64, 8), 256, 0, stream>>>(pairP, h2P, Bp3, b_left3, out);
}